// Round 1
// baseline (3291.833 us; speedup 1.0000x reference)
//
#include <hip/hip_runtime.h>

// Problem constants
constexpr int NU = 100000;
constexpr int NI = 50000;
constexpr int NN = 150000;          // NU + NI
constexpr int EMB = 64;
constexpr size_t U64 = (size_t)NU * EMB;   // 6,400,000
constexpr size_t I64 = (size_t)NI * EMB;   // 3,200,000
constexpr size_t N64 = (size_t)NN * EMB;   // 9,600,000

// ---------------- init: acc = h0 = concat(user_emb, item_emb); h1 = 0 ----------------
__global__ void init_k(const float4* __restrict__ ue, const float4* __restrict__ ie,
                       float4* __restrict__ acc, float4* __restrict__ h0,
                       float4* __restrict__ h1) {
    int i = blockIdx.x * blockDim.x + threadIdx.x;
    const int n4 = (int)(N64 / 4);
    if (i >= n4) return;
    const int u4 = (int)(U64 / 4);
    float4 v = (i < u4) ? ue[i] : ie[i - u4];
    acc[i] = v;
    h0[i] = v;
    h1[i] = make_float4(0.f, 0.f, 0.f, 0.f);
}

// ---------------- SpMM scatter: y[row] += x[col] * val (one wave per edge) ----------------
__global__ void spmm_k(const int* __restrict__ rows, const int* __restrict__ cols,
                       const float* __restrict__ vals,
                       const float* __restrict__ x, float* __restrict__ y, int nnz) {
    int e = (blockIdx.x * blockDim.x + threadIdx.x) >> 6;
    int lane = threadIdx.x & 63;
    if (e >= nnz) return;
    int r = rows[e];
    int c = cols[e];
    float v = vals[e];
    float g = x[(size_t)c * EMB + lane] * v;
    atomicAdd(&y[(size_t)r * EMB + lane], g);
}

// ---------------- acc += hin; hz = 0 ----------------
__global__ void addzero_k(float4* __restrict__ acc, const float4* __restrict__ hin,
                          float4* __restrict__ hz) {
    int i = blockIdx.x * blockDim.x + threadIdx.x;
    const int n4 = (int)(N64 / 4);
    if (i >= n4) return;
    float4 a = acc[i];
    float4 b = hin[i];
    a.x += b.x; a.y += b.y; a.z += b.z; a.w += b.w;
    acc[i] = a;
    hz[i] = make_float4(0.f, 0.f, 0.f, 0.f);
}

// ---------------- final: combined = (acc + hlast)*0.25 (in place over acc=dout);
//                  masked_user = combined * mask for user rows ----------------
__global__ void final_k(float4* __restrict__ acc_io, const float4* __restrict__ hlast,
                        const float4* __restrict__ mask, float4* __restrict__ masked_out) {
    int i = blockIdx.x * blockDim.x + threadIdx.x;
    const int n4 = (int)(N64 / 4);
    if (i >= n4) return;
    float4 a = acc_io[i];
    float4 h = hlast[i];
    float4 c;
    c.x = (a.x + h.x) * 0.25f;
    c.y = (a.y + h.y) * 0.25f;
    c.z = (a.z + h.z) * 0.25f;
    c.w = (a.w + h.w) * 0.25f;
    acc_io[i] = c;
    const int u4 = (int)(U64 / 4);
    if (i < u4) {
        float4 m = mask[i];
        float4 mm;
        mm.x = c.x * m.x;
        mm.y = c.y * m.y;
        mm.z = c.z * m.z;
        mm.w = c.w * m.w;
        masked_out[i] = mm;
    }
}

// ---------------- mask copy ----------------
__global__ void copy_k(const float4* __restrict__ src, float4* __restrict__ dst, int n4) {
    int i = blockIdx.x * blockDim.x + threadIdx.x;
    if (i >= n4) return;
    dst[i] = src[i];
}

// ---------------- predicted = relu(masked @ W + b), one wave per row ----------------
__global__ __launch_bounds__(256) void attr_gemm_k(const float* __restrict__ masked,
                                                   const float* __restrict__ W,
                                                   const float* __restrict__ b,
                                                   float* __restrict__ out) {
    __shared__ float Wl[64 * 64];
    __shared__ float bl[64];
    int t = threadIdx.x;
    #pragma unroll
    for (int k = 0; k < 16; ++k) Wl[t + 256 * k] = W[t + 256 * k];
    if (t < 64) bl[t] = b[t];
    __syncthreads();
    int wave = t >> 6, lane = t & 63;
    int row = blockIdx.x * 4 + wave;
    if (row >= NU) return;
    float mval = masked[(size_t)row * EMB + lane];
    float sum = bl[lane];
    #pragma unroll
    for (int k = 0; k < 64; ++k) {
        sum += __shfl(mval, k) * Wl[k * 64 + lane];
    }
    out[(size_t)row * EMB + lane] = fmaxf(sum, 0.f);
}

extern "C" void kernel_launch(void* const* d_in, const int* in_sizes, int n_in,
                              void* d_out, int out_size, void* d_ws, size_t ws_size,
                              hipStream_t stream) {
    const float* user_emb = (const float*)d_in[0];
    const float* item_emb = (const float*)d_in[1];
    const int*   rows     = (const int*)d_in[2];
    const int*   cols     = (const int*)d_in[3];
    const float* vals     = (const float*)d_in[4];
    const float* mask     = (const float*)d_in[5];
    const float* W        = (const float*)d_in[6];
    const float* b        = (const float*)d_in[7];
    float* out = (float*)d_out;
    const int nnz = in_sizes[2];

    // Scratch packed into d_out (out_size = 3*N64 floats exactly):
    //   acc = out[0 .. N64)            -> becomes user_final||item_final
    //   h0  = out[N64 .. 2*N64)        -> later overwritten by masked/predicted
    //   h1  = out[2*N64 .. 3*N64)      -> later overwritten by predicted/mask
    float* acc = out;
    float* h0  = out + N64;
    float* h1  = out + 2 * N64;
    float* masked_out = out + N64;               // [9.6M, 16M)
    float* pred_out   = out + N64 + U64;         // [16M, 22.4M)
    float* mask_out   = out + N64 + 2 * U64;     // [22.4M, 28.8M)

    const int n4 = (int)(N64 / 4);               // 2.4M float4s
    const int blk = 256;
    const int grid_n4 = (n4 + blk - 1) / blk;

    // 1. init acc=h0=emb, h1=0
    init_k<<<grid_n4, blk, 0, stream>>>((const float4*)user_emb, (const float4*)item_emb,
                                        (float4*)acc, (float4*)h0, (float4*)h1);

    const long long scatter_threads = (long long)nnz * 64;
    const int grid_sc = (int)((scatter_threads + blk - 1) / blk);

    // 2. layer 1: h1 = A * h0 ; acc += h1 ; h0 = 0
    spmm_k<<<grid_sc, blk, 0, stream>>>(rows, cols, vals, h0, h1, nnz);
    addzero_k<<<grid_n4, blk, 0, stream>>>((float4*)acc, (const float4*)h1, (float4*)h0);

    // 3. layer 2: h0 = A * h1 ; acc += h0 ; h1 = 0
    spmm_k<<<grid_sc, blk, 0, stream>>>(rows, cols, vals, h1, h0, nnz);
    addzero_k<<<grid_n4, blk, 0, stream>>>((float4*)acc, (const float4*)h0, (float4*)h1);

    // 4. layer 3: h1 = A * h0
    spmm_k<<<grid_sc, blk, 0, stream>>>(rows, cols, vals, h0, h1, nnz);

    // 5. combined = (acc + h1) * 0.25 in place; masked_user written
    final_k<<<grid_n4, blk, 0, stream>>>((float4*)acc, (const float4*)h1,
                                         (const float4*)mask, (float4*)masked_out);

    // 6. predicted = relu(masked @ W + b)
    attr_gemm_k<<<NU / 4, blk, 0, stream>>>(masked_out, W, b, pred_out);

    // 7. mask copy
    const int mu4 = (int)(U64 / 4);
    copy_k<<<(mu4 + blk - 1) / blk, blk, 0, stream>>>((const float4*)mask, (float4*)mask_out,
                                                      mu4);
}

// Round 2
// 1437.252 us; speedup vs baseline: 2.2904x; 2.2904x over previous
//
#include <hip/hip_runtime.h>

constexpr int NU = 100000;
constexpr int NI = 50000;
constexpr int NN = 150000;
constexpr int EMB = 64;
constexpr size_t U64 = (size_t)NU * EMB;   // 6,400,000
constexpr size_t N64 = (size_t)NN * EMB;   // 9,600,000

// ======================= CSR build =======================

__global__ void zero_k(int4* __restrict__ p, int n) {
    int i = blockIdx.x * blockDim.x + threadIdx.x;
    if (i < n) p[i] = make_int4(0, 0, 0, 0);
}

__global__ void hist_k(const int* __restrict__ rows, int* __restrict__ counts, int nnz) {
    int i = blockIdx.x * blockDim.x + threadIdx.x;
    if (i < nnz) atomicAdd(&counts[rows[i]], 1);
}

// Exclusive scan of ceil(count/16)*16 over NN rows; writes offs[0..NN] and cursor[0..NN)
__global__ __launch_bounds__(1024) void scan_k(const int* __restrict__ counts,
                                               int* __restrict__ offs,
                                               int* __restrict__ cursor) {
    constexpr int CHUNK = (NN + 1023) / 1024;   // 147
    __shared__ int part[1024];
    int t = threadIdx.x;
    int b = t * CHUNK;
    int e = min(b + CHUNK, NN);
    int sum = 0;
    for (int i = b; i < e; ++i) sum += (counts[i] + 15) & ~15;
    part[t] = sum;
    __syncthreads();
    for (int d = 1; d < 1024; d <<= 1) {
        int v = (t >= d) ? part[t - d] : 0;
        __syncthreads();
        part[t] += v;
        __syncthreads();
    }
    int run = (t == 0) ? 0 : part[t - 1];
    for (int i = b; i < e; ++i) {
        offs[i] = run;
        cursor[i] = run;
        run += (counts[i] + 15) & ~15;
    }
    if (b < NN && e == NN) offs[NN] = run;
}

__global__ void fill_k(const int* __restrict__ rows, const int* __restrict__ cols,
                       const float* __restrict__ vals, int* __restrict__ cursor,
                       int2* __restrict__ edges, int nnz) {
    int i = blockIdx.x * blockDim.x + threadIdx.x;
    if (i >= nnz) return;
    int r = rows[i];
    int pos = atomicAdd(&cursor[r], 1);
    edges[pos] = make_int2(cols[i], __float_as_int(vals[i]));
}

// ======================= CSR row-gather SpMM =======================
// One wave per row. 4 groups of 16 lanes; each lane holds float4 (4 dims).
// MODE 0: y = A*emb; acc = emb_row + y     (x split user/item)
// MODE 1: y = A*x;   acc += y
// MODE 2: acc = (acc + A*x) * 0.25         (y unused)
template<int MODE>
__global__ __launch_bounds__(256) void spmm4_k(
    const int* __restrict__ offs, const int2* __restrict__ edges,
    const float4* __restrict__ xu, const float4* __restrict__ xi,
    float4* __restrict__ y, float4* __restrict__ acc) {
    int w = (blockIdx.x * 256 + (int)threadIdx.x) >> 6;
    int lane = threadIdx.x & 63;
    if (w >= NN) return;
    int beg = offs[w], end = offs[w + 1];
    int g = lane >> 4, gl = lane & 15;
    float4 s = make_float4(0.f, 0.f, 0.f, 0.f);
    for (int p = beg; p < end; p += 16) {
        int2 e = make_int2(0, 0);
        if (lane < 16) e = edges[p + lane];
        #pragma unroll
        for (int j = 0; j < 4; ++j) {
            int src = g * 4 + j;
            int c = __shfl(e.x, src);
            float v = __int_as_float(__shfl(e.y, src));
            float4 xv;
            if (MODE == 0) {
                const float4* bx = (c < NU) ? xu : xi;
                int cc = (c < NU) ? c : c - NU;
                xv = bx[(size_t)cc * 16 + gl];
            } else {
                xv = xu[(size_t)c * 16 + gl];
            }
            s.x += v * xv.x; s.y += v * xv.y; s.z += v * xv.z; s.w += v * xv.w;
        }
    }
    #pragma unroll
    for (int d = 16; d <= 32; d <<= 1) {
        s.x += __shfl_xor(s.x, d);
        s.y += __shfl_xor(s.y, d);
        s.z += __shfl_xor(s.z, d);
        s.w += __shfl_xor(s.w, d);
    }
    if (lane < 16) {
        size_t o = (size_t)w * 16 + lane;
        if (MODE == 0) {
            const float4* be = (w < NU) ? xu : xi;
            int ww = (w < NU) ? w : w - NU;
            float4 em = be[(size_t)ww * 16 + lane];
            y[o] = s;
            acc[o] = make_float4(em.x + s.x, em.y + s.y, em.z + s.z, em.w + s.w);
        } else if (MODE == 1) {
            y[o] = s;
            float4 a = acc[o];
            acc[o] = make_float4(a.x + s.x, a.y + s.y, a.z + s.z, a.w + s.w);
        } else {
            float4 a = acc[o];
            acc[o] = make_float4((a.x + s.x) * 0.25f, (a.y + s.y) * 0.25f,
                                 (a.z + s.z) * 0.25f, (a.w + s.w) * 0.25f);
        }
    }
}

// ======================= epilogue =======================

__global__ void epi_k(const float4* __restrict__ comb, const float4* __restrict__ mask,
                      float4* __restrict__ masked, float4* __restrict__ mout) {
    int i = blockIdx.x * blockDim.x + threadIdx.x;
    const int u4 = (int)(U64 / 4);
    if (i >= u4) return;
    float4 c = comb[i], m = mask[i];
    masked[i] = make_float4(c.x * m.x, c.y * m.y, c.z * m.z, c.w * m.w);
    mout[i] = m;
}

__global__ __launch_bounds__(256) void attr_gemm_k(const float* __restrict__ masked,
                                                   const float* __restrict__ W,
                                                   const float* __restrict__ b,
                                                   float* __restrict__ out) {
    __shared__ float Wl[64 * 64];
    __shared__ float bl[64];
    int t = threadIdx.x;
    #pragma unroll
    for (int k = 0; k < 16; ++k) Wl[t + 256 * k] = W[t + 256 * k];
    if (t < 64) bl[t] = b[t];
    __syncthreads();
    int wave = t >> 6, lane = t & 63;
    int row = blockIdx.x * 4 + wave;
    if (row >= NU) return;
    float mval = masked[(size_t)row * EMB + lane];
    float sum = bl[lane];
    #pragma unroll
    for (int k = 0; k < 64; ++k) {
        sum += __shfl(mval, k) * Wl[k * 64 + lane];
    }
    out[(size_t)row * EMB + lane] = fmaxf(sum, 0.f);
}

// ======================= fallback (round-0 atomic path) =======================

__global__ void init_k(const float4* __restrict__ ue, const float4* __restrict__ ie,
                       float4* __restrict__ acc, float4* __restrict__ h0,
                       float4* __restrict__ h1) {
    int i = blockIdx.x * blockDim.x + threadIdx.x;
    const int n4 = (int)(N64 / 4);
    if (i >= n4) return;
    const int u4 = (int)(U64 / 4);
    float4 v = (i < u4) ? ue[i] : ie[i - u4];
    acc[i] = v; h0[i] = v; h1[i] = make_float4(0.f, 0.f, 0.f, 0.f);
}

__global__ void spmm_atomic_k(const int* __restrict__ rows, const int* __restrict__ cols,
                              const float* __restrict__ vals,
                              const float* __restrict__ x, float* __restrict__ y, int nnz) {
    int e = (blockIdx.x * blockDim.x + threadIdx.x) >> 6;
    int lane = threadIdx.x & 63;
    if (e >= nnz) return;
    int r = rows[e]; int c = cols[e]; float v = vals[e];
    atomicAdd(&y[(size_t)r * EMB + lane], x[(size_t)c * EMB + lane] * v);
}

__global__ void addzero_k(float4* __restrict__ acc, const float4* __restrict__ hin,
                          float4* __restrict__ hz) {
    int i = blockIdx.x * blockDim.x + threadIdx.x;
    const int n4 = (int)(N64 / 4);
    if (i >= n4) return;
    float4 a = acc[i]; float4 b = hin[i];
    a.x += b.x; a.y += b.y; a.z += b.z; a.w += b.w;
    acc[i] = a; hz[i] = make_float4(0.f, 0.f, 0.f, 0.f);
}

__global__ void final_k(float4* __restrict__ acc_io, const float4* __restrict__ hlast,
                        const float4* __restrict__ mask, float4* __restrict__ masked_out) {
    int i = blockIdx.x * blockDim.x + threadIdx.x;
    const int n4 = (int)(N64 / 4);
    if (i >= n4) return;
    float4 a = acc_io[i]; float4 h = hlast[i];
    float4 c = make_float4((a.x + h.x) * 0.25f, (a.y + h.y) * 0.25f,
                           (a.z + h.z) * 0.25f, (a.w + h.w) * 0.25f);
    acc_io[i] = c;
    const int u4 = (int)(U64 / 4);
    if (i < u4) {
        float4 m = mask[i];
        masked_out[i] = make_float4(c.x * m.x, c.y * m.y, c.z * m.z, c.w * m.w);
    }
}

__global__ void copy_k(const float4* __restrict__ src, float4* __restrict__ dst, int n4) {
    int i = blockIdx.x * blockDim.x + threadIdx.x;
    if (i < n4) dst[i] = src[i];
}

// ======================= launch =======================

extern "C" void kernel_launch(void* const* d_in, const int* in_sizes, int n_in,
                              void* d_out, int out_size, void* d_ws, size_t ws_size,
                              hipStream_t stream) {
    const float* user_emb = (const float*)d_in[0];
    const float* item_emb = (const float*)d_in[1];
    const int*   rows     = (const int*)d_in[2];
    const int*   cols     = (const int*)d_in[3];
    const float* vals     = (const float*)d_in[4];
    const float* mask     = (const float*)d_in[5];
    const float* W        = (const float*)d_in[6];
    const float* b        = (const float*)d_in[7];
    float* out = (float*)d_out;
    const int nnz = in_sizes[2];

    float* acc = out;                       // -> user_final || item_final
    float* h0  = out + N64;
    float* h1  = out + 2 * N64;
    float* masked_out = out + N64;          // after h0 dead
    float* pred_out   = out + N64 + U64;
    float* mask_out   = out + N64 + 2 * U64;

    const int blk = 256;
    const int n4 = (int)(N64 / 4);
    const int grid_n4 = (n4 + blk - 1) / blk;
    const int u4 = (int)(U64 / 4);

    // workspace carve
    const size_t AUX = 150016;              // >= NN+1, 16B-aligned blocks
    int* offs   = (int*)d_ws;
    int* cursor = offs + AUX;
    int* counts = cursor + AUX;
    int2* edges = (int2*)(counts + AUX);
    const size_t padMax = (size_t)nnz + (size_t)NN * 15;
    const size_t need = AUX * 3 * 4 + padMax * 8 + 32;

    if (ws_size >= need) {
        // ---- fast path: device CSR + gather SpMM ----
        const int c4 = (int)(AUX / 4);
        zero_k<<<(c4 + blk - 1) / blk, blk, 0, stream>>>((int4*)counts, c4);
        const int ez4 = (int)((padMax * 2 + 3) / 4);
        zero_k<<<(ez4 + blk - 1) / blk, blk, 0, stream>>>((int4*)edges, ez4);
        hist_k<<<(nnz + blk - 1) / blk, blk, 0, stream>>>(rows, counts, nnz);
        scan_k<<<1, 1024, 0, stream>>>(counts, offs, cursor);
        fill_k<<<(nnz + blk - 1) / blk, blk, 0, stream>>>(rows, cols, vals, cursor, edges, nnz);

        const int grid_sp = (NN * 64) / blk;   // 37500
        spmm4_k<0><<<grid_sp, blk, 0, stream>>>(offs, edges,
            (const float4*)user_emb, (const float4*)item_emb,
            (float4*)h1, (float4*)acc);
        spmm4_k<1><<<grid_sp, blk, 0, stream>>>(offs, edges,
            (const float4*)h1, nullptr, (float4*)h0, (float4*)acc);
        spmm4_k<2><<<grid_sp, blk, 0, stream>>>(offs, edges,
            (const float4*)h0, nullptr, (float4*)acc, (float4*)acc);

        epi_k<<<(u4 + blk - 1) / blk, blk, 0, stream>>>((const float4*)acc,
            (const float4*)mask, (float4*)masked_out, (float4*)mask_out);
        attr_gemm_k<<<NU / 4, blk, 0, stream>>>(masked_out, W, b, pred_out);
    } else {
        // ---- fallback: atomic scatter path ----
        init_k<<<grid_n4, blk, 0, stream>>>((const float4*)user_emb, (const float4*)item_emb,
                                            (float4*)acc, (float4*)h0, (float4*)h1);
        const long long st = (long long)nnz * 64;
        const int grid_sc = (int)((st + blk - 1) / blk);
        spmm_atomic_k<<<grid_sc, blk, 0, stream>>>(rows, cols, vals, h0, h1, nnz);
        addzero_k<<<grid_n4, blk, 0, stream>>>((float4*)acc, (const float4*)h1, (float4*)h0);
        spmm_atomic_k<<<grid_sc, blk, 0, stream>>>(rows, cols, vals, h1, h0, nnz);
        addzero_k<<<grid_n4, blk, 0, stream>>>((float4*)acc, (const float4*)h0, (float4*)h1);
        spmm_atomic_k<<<grid_sc, blk, 0, stream>>>(rows, cols, vals, h0, h1, nnz);
        final_k<<<grid_n4, blk, 0, stream>>>((float4*)acc, (const float4*)h1,
                                             (const float4*)mask, (float4*)masked_out);
        attr_gemm_k<<<NU / 4, blk, 0, stream>>>(masked_out, W, b, pred_out);
        copy_k<<<(u4 + blk - 1) / blk, blk, 0, stream>>>((const float4*)mask,
                                                         (float4*)mask_out, u4);
    }
}

// Round 3
// 1382.754 us; speedup vs baseline: 2.3806x; 1.0394x over previous
//
#include <hip/hip_runtime.h>

constexpr int NU = 100000;
constexpr int NI = 50000;
constexpr int NN = 150000;
constexpr int EMB = 64;
constexpr size_t U64 = (size_t)NU * EMB;   // 6,400,000
constexpr size_t N64 = (size_t)NN * EMB;   // 9,600,000
constexpr int NB = (NN + 63) >> 6;         // 2344 buckets of 64 rows

// ---------- bf16 pack (RNE) ----------
__device__ inline unsigned int bfp(float a, float b) {
    unsigned int ua = __float_as_uint(a), ub = __float_as_uint(b);
    ua += 0x7fffu + ((ua >> 16) & 1u);
    ub += 0x7fffu + ((ub >> 16) & 1u);
    return (ua >> 16) | (ub & 0xffff0000u);
}

// ======================= CSR build =======================

__global__ void zero_k(int4* __restrict__ p, int n) {
    int i = blockIdx.x * blockDim.x + threadIdx.x;
    if (i < n) p[i] = make_int4(0, 0, 0, 0);
}

__global__ void hist_k(const int* __restrict__ rows, int* __restrict__ counts, int nnz) {
    int i = blockIdx.x * blockDim.x + threadIdx.x;
    if (i < nnz) atomicAdd(&counts[rows[i]], 1);
}

// exact exclusive scan over NN row counts -> offs[0..NN]
__global__ __launch_bounds__(1024) void scan_k(const int* __restrict__ counts,
                                               int* __restrict__ offs) {
    constexpr int CHUNK = (NN + 1023) / 1024;   // 147
    __shared__ int part[1024];
    int t = threadIdx.x;
    int b = t * CHUNK;
    int e = min(b + CHUNK, NN);
    int sum = 0;
    for (int i = b; i < e; ++i) sum += counts[i];
    part[t] = sum;
    __syncthreads();
    for (int d = 1; d < 1024; d <<= 1) {
        int v = (t >= d) ? part[t - d] : 0;
        __syncthreads();
        part[t] += v;
        __syncthreads();
    }
    int run = (t == 0) ? 0 : part[t - 1];
    for (int i = b; i < e; ++i) { offs[i] = run; run += counts[i]; }
    if (b < NN && e == NN) offs[NN] = run;
}

__global__ void bcur_k(const int* __restrict__ offs, int* __restrict__ bcur) {
    int b = blockIdx.x * blockDim.x + threadIdx.x;
    if (b < NB) bcur[b] = offs[min(b * 64, NN)];
}

// pass A: scatter edges into coarse 64-row buckets (dense sequential fill per bucket)
__global__ void passA_k(const int* __restrict__ rows, const int* __restrict__ cols,
                        const float* __restrict__ vals, int* __restrict__ bcur,
                        int2* __restrict__ stage, int nnz) {
    int i = blockIdx.x * blockDim.x + threadIdx.x;
    if (i >= nnz) return;
    int r = rows[i];
    int pos = atomicAdd(&bcur[r >> 6], 1);
    stage[pos] = make_int2(cols[i] | ((r & 63) << 18), __float_as_int(vals[i]));
}

// pass B: within-bucket sort to exact CSR row positions (LDS cursors)
__global__ __launch_bounds__(256) void passB_k(const int2* __restrict__ stage,
                                               const int* __restrict__ offs,
                                               int2* __restrict__ edges) {
    __shared__ int lcur[64];
    int b = blockIdx.x;
    int t = threadIdx.x;
    if (t < 64) lcur[t] = offs[min(b * 64 + t, NN)];
    __syncthreads();
    int beg = offs[min(b * 64, NN)];
    int end = offs[min(b * 64 + 64, NN)];
    for (int i = beg + t; i < end; i += 256) {
        int2 e = stage[i];
        int lrow = (e.x >> 18) & 63;
        int pos = atomicAdd(&lcur[lrow], 1);
        edges[pos] = make_int2(e.x & 0x3ffff, e.y);
    }
}

// ======================= init: acc = emb (f32), hb0 = bf16(emb) =======================
__global__ void init_k(const float4* __restrict__ ue, const float4* __restrict__ ie,
                       float4* __restrict__ acc, uint2* __restrict__ hb0) {
    int i = blockIdx.x * blockDim.x + threadIdx.x;
    const int n4 = (int)(N64 / 4);
    if (i >= n4) return;
    const int u4 = (int)(U64 / 4);
    float4 v = (i < u4) ? ue[i] : ie[i - u4];
    acc[i] = v;
    hb0[i] = make_uint2(bfp(v.x, v.y), bfp(v.z, v.w));
}

// ======================= CSR row-gather SpMM (bf16 x) =======================
// One wave per row; 4 groups x 16 lanes; lane holds 4 dims.
// MODE 1: yb = bf16(A*x); acc += A*x
// MODE 2: acc = (acc + A*x) * 0.25
template<int MODE>
__global__ __launch_bounds__(256) void spmm_g(
    const int* __restrict__ offs, const int2* __restrict__ edges,
    const unsigned int* __restrict__ xb,
    uint2* __restrict__ yb, float4* __restrict__ acc) {
    int w = (blockIdx.x * 256 + (int)threadIdx.x) >> 6;
    int lane = threadIdx.x & 63;
    if (w >= NN) return;
    int beg = offs[w], end = offs[w + 1];
    int g = lane >> 4, gl = lane & 15;
    float4 s = make_float4(0.f, 0.f, 0.f, 0.f);
    for (int p = beg; p < end; p += 16) {
        int idx = p + lane;
        int2 e = (lane < 16 && idx < end) ? edges[idx] : make_int2(0, 0);
        #pragma unroll
        for (int j = 0; j < 4; ++j) {
            int src = g * 4 + j;
            int c = __shfl(e.x, src);
            float v = __int_as_float(__shfl(e.y, src));
            uint2 u = *(const uint2*)(xb + (size_t)c * 32 + gl * 2);
            float x0 = __uint_as_float(u.x << 16);
            float x1 = __uint_as_float(u.x & 0xffff0000u);
            float x2 = __uint_as_float(u.y << 16);
            float x3 = __uint_as_float(u.y & 0xffff0000u);
            s.x += v * x0; s.y += v * x1; s.z += v * x2; s.w += v * x3;
        }
    }
    #pragma unroll
    for (int d = 16; d <= 32; d <<= 1) {
        s.x += __shfl_xor(s.x, d);
        s.y += __shfl_xor(s.y, d);
        s.z += __shfl_xor(s.z, d);
        s.w += __shfl_xor(s.w, d);
    }
    if (lane < 16) {
        size_t o = (size_t)w * 16 + gl;
        if (MODE == 1) {
            yb[o] = make_uint2(bfp(s.x, s.y), bfp(s.z, s.w));
            float4 a = acc[o];
            acc[o] = make_float4(a.x + s.x, a.y + s.y, a.z + s.z, a.w + s.w);
        } else {
            float4 a = acc[o];
            acc[o] = make_float4((a.x + s.x) * 0.25f, (a.y + s.y) * 0.25f,
                                 (a.z + s.z) * 0.25f, (a.w + s.w) * 0.25f);
        }
    }
}

// ======================= epilogue =======================

__global__ void epi_k(const float4* __restrict__ comb, const float4* __restrict__ mask,
                      float4* __restrict__ masked, float4* __restrict__ mout) {
    int i = blockIdx.x * blockDim.x + threadIdx.x;
    const int u4 = (int)(U64 / 4);
    if (i >= u4) return;
    float4 c = comb[i], m = mask[i];
    masked[i] = make_float4(c.x * m.x, c.y * m.y, c.z * m.z, c.w * m.w);
    mout[i] = m;
}

__global__ __launch_bounds__(256) void attr_gemm_k(const float* __restrict__ masked,
                                                   const float* __restrict__ W,
                                                   const float* __restrict__ b,
                                                   float* __restrict__ out) {
    __shared__ float Wl[64 * 64];
    __shared__ float bl[64];
    int t = threadIdx.x;
    #pragma unroll
    for (int k = 0; k < 16; ++k) Wl[t + 256 * k] = W[t + 256 * k];
    if (t < 64) bl[t] = b[t];
    __syncthreads();
    int wave = t >> 6, lane = t & 63;
    int row = blockIdx.x * 4 + wave;
    if (row >= NU) return;
    float mval = masked[(size_t)row * EMB + lane];
    float sum = bl[lane];
    #pragma unroll
    for (int k = 0; k < 64; ++k) {
        sum += __shfl(mval, k) * Wl[k * 64 + lane];
    }
    out[(size_t)row * EMB + lane] = fmaxf(sum, 0.f);
}

// ======================= fallback (atomic path) =======================

__global__ void finit_k(const float4* __restrict__ ue, const float4* __restrict__ ie,
                        float4* __restrict__ acc, float4* __restrict__ h0,
                        float4* __restrict__ h1) {
    int i = blockIdx.x * blockDim.x + threadIdx.x;
    const int n4 = (int)(N64 / 4);
    if (i >= n4) return;
    const int u4 = (int)(U64 / 4);
    float4 v = (i < u4) ? ue[i] : ie[i - u4];
    acc[i] = v; h0[i] = v; h1[i] = make_float4(0.f, 0.f, 0.f, 0.f);
}

__global__ void spmm_atomic_k(const int* __restrict__ rows, const int* __restrict__ cols,
                              const float* __restrict__ vals,
                              const float* __restrict__ x, float* __restrict__ y, int nnz) {
    int e = (blockIdx.x * blockDim.x + threadIdx.x) >> 6;
    int lane = threadIdx.x & 63;
    if (e >= nnz) return;
    int r = rows[e]; int c = cols[e]; float v = vals[e];
    atomicAdd(&y[(size_t)r * EMB + lane], x[(size_t)c * EMB + lane] * v);
}

__global__ void addzero_k(float4* __restrict__ acc, const float4* __restrict__ hin,
                          float4* __restrict__ hz) {
    int i = blockIdx.x * blockDim.x + threadIdx.x;
    const int n4 = (int)(N64 / 4);
    if (i >= n4) return;
    float4 a = acc[i]; float4 b = hin[i];
    a.x += b.x; a.y += b.y; a.z += b.z; a.w += b.w;
    acc[i] = a; hz[i] = make_float4(0.f, 0.f, 0.f, 0.f);
}

__global__ void final_k(float4* __restrict__ acc_io, const float4* __restrict__ hlast,
                        const float4* __restrict__ mask, float4* __restrict__ masked_out) {
    int i = blockIdx.x * blockDim.x + threadIdx.x;
    const int n4 = (int)(N64 / 4);
    if (i >= n4) return;
    float4 a = acc_io[i]; float4 h = hlast[i];
    float4 c = make_float4((a.x + h.x) * 0.25f, (a.y + h.y) * 0.25f,
                           (a.z + h.z) * 0.25f, (a.w + h.w) * 0.25f);
    acc_io[i] = c;
    const int u4 = (int)(U64 / 4);
    if (i < u4) {
        float4 m = mask[i];
        masked_out[i] = make_float4(c.x * m.x, c.y * m.y, c.z * m.z, c.w * m.w);
    }
}

__global__ void copy_k(const float4* __restrict__ src, float4* __restrict__ dst, int n4) {
    int i = blockIdx.x * blockDim.x + threadIdx.x;
    if (i < n4) dst[i] = src[i];
}

// ======================= launch =======================

extern "C" void kernel_launch(void* const* d_in, const int* in_sizes, int n_in,
                              void* d_out, int out_size, void* d_ws, size_t ws_size,
                              hipStream_t stream) {
    const float* user_emb = (const float*)d_in[0];
    const float* item_emb = (const float*)d_in[1];
    const int*   rows     = (const int*)d_in[2];
    const int*   cols     = (const int*)d_in[3];
    const float* vals     = (const float*)d_in[4];
    const float* mask     = (const float*)d_in[5];
    const float* W        = (const float*)d_in[6];
    const float* b        = (const float*)d_in[7];
    float* out = (float*)d_out;
    const int nnz = in_sizes[2];

    float* acc = out;                         // -> user_final || item_final
    float* masked_out = out + N64;
    float* pred_out   = out + N64 + U64;
    float* mask_out   = out + N64 + 2 * U64;

    const int blk = 256;
    const int n4 = (int)(N64 / 4);
    const int grid_n4 = (n4 + blk - 1) / blk;
    const int u4 = (int)(U64 / 4);

    // ws carve: counts | offs | bcur | edges
    const size_t CNT = 150016;                // >= NN+1
    int* counts = (int*)d_ws;
    int* offs   = counts + CNT;
    int* bcur   = offs + CNT;
    int2* edges = (int2*)(bcur + 2560);
    const size_t need = (CNT * 2 + 2560) * 4 + (size_t)nnz * 8 + 64;

    if (ws_size >= need) {
        // stage lives in d_out's h-region (dead until init_k)
        int2* stage = (int2*)(out + N64);
        // bf16 h buffers, also in d_out's h-region (live after stage is dead)
        uint2* hb0 = (uint2*)(out + N64);                 // N64/4 uint2 = 19.2 MB
        uint2* hb1 = hb0 + (N64 / 4);

        zero_k<<<(int)((CNT / 4 + blk - 1) / blk), blk, 0, stream>>>((int4*)counts,
                                                                     (int)(CNT / 4));
        hist_k<<<(nnz + blk - 1) / blk, blk, 0, stream>>>(rows, counts, nnz);
        scan_k<<<1, 1024, 0, stream>>>(counts, offs);
        bcur_k<<<(NB + blk - 1) / blk, blk, 0, stream>>>(offs, bcur);
        passA_k<<<(nnz + blk - 1) / blk, blk, 0, stream>>>(rows, cols, vals, bcur,
                                                           stage, nnz);
        passB_k<<<NB, blk, 0, stream>>>(stage, offs, edges);

        init_k<<<grid_n4, blk, 0, stream>>>((const float4*)user_emb,
                                            (const float4*)item_emb,
                                            (float4*)acc, (uint2*)hb0);

        const int grid_sp = (int)(((size_t)NN * 64) / blk);   // 37500
        spmm_g<1><<<grid_sp, blk, 0, stream>>>(offs, edges, (const unsigned int*)hb0,
                                               hb1, (float4*)acc);
        spmm_g<1><<<grid_sp, blk, 0, stream>>>(offs, edges, (const unsigned int*)hb1,
                                               hb0, (float4*)acc);
        spmm_g<2><<<grid_sp, blk, 0, stream>>>(offs, edges, (const unsigned int*)hb0,
                                               nullptr, (float4*)acc);

        epi_k<<<(u4 + blk - 1) / blk, blk, 0, stream>>>((const float4*)acc,
            (const float4*)mask, (float4*)masked_out, (float4*)mask_out);
        attr_gemm_k<<<NU / 4, blk, 0, stream>>>(masked_out, W, b, pred_out);
    } else {
        // fallback: atomic scatter path entirely in d_out
        float* h0 = out + N64;
        float* h1 = out + 2 * N64;
        finit_k<<<grid_n4, blk, 0, stream>>>((const float4*)user_emb,
                                             (const float4*)item_emb,
                                             (float4*)acc, (float4*)h0, (float4*)h1);
        const long long st = (long long)nnz * 64;
        const int grid_sc = (int)((st + blk - 1) / blk);
        spmm_atomic_k<<<grid_sc, blk, 0, stream>>>(rows, cols, vals, h0, h1, nnz);
        addzero_k<<<grid_n4, blk, 0, stream>>>((float4*)acc, (const float4*)h1, (float4*)h0);
        spmm_atomic_k<<<grid_sc, blk, 0, stream>>>(rows, cols, vals, h1, h0, nnz);
        addzero_k<<<grid_n4, blk, 0, stream>>>((float4*)acc, (const float4*)h0, (float4*)h1);
        spmm_atomic_k<<<grid_sc, blk, 0, stream>>>(rows, cols, vals, h0, h1, nnz);
        final_k<<<grid_n4, blk, 0, stream>>>((float4*)acc, (const float4*)h1,
                                             (const float4*)mask, (float4*)masked_out);
        attr_gemm_k<<<NU / 4, blk, 0, stream>>>(masked_out, W, b, pred_out);
        copy_k<<<(u4 + blk - 1) / blk, blk, 0, stream>>>((const float4*)mask,
                                                         (float4*)mask_out, u4);
    }
}

// Round 4
// 1011.560 us; speedup vs baseline: 3.2542x; 1.3670x over previous
//
#include <hip/hip_runtime.h>

constexpr int NU = 100000;
constexpr int NI = 50000;
constexpr int NN = 150000;
constexpr int EMB = 64;
constexpr size_t U64 = (size_t)NU * EMB;   // 6,400,000
constexpr size_t N64 = (size_t)NN * EMB;   // 9,600,000
constexpr int NBC = (NN + 255) >> 8;       // 586 coarse buckets of 256 rows
constexpr int CHUNK_E = 16384;             // edges per sort block

// ---------- bf16 pack (RNE) ----------
__device__ inline unsigned int bfp(float a, float b) {
    unsigned int ua = __float_as_uint(a), ub = __float_as_uint(b);
    ua += 0x7fffu + ((ua >> 16) & 1u);
    ub += 0x7fffu + ((ub >> 16) & 1u);
    return (ua >> 16) | (ub & 0xffff0000u);
}

// ======================= CSR build =======================

__global__ void zero_k(int4* __restrict__ p, int n) {
    int i = blockIdx.x * blockDim.x + threadIdx.x;
    if (i < n) p[i] = make_int4(0, 0, 0, 0);
}

__global__ void hist_k(const int* __restrict__ rows, int* __restrict__ counts, int nnz) {
    int i = blockIdx.x * blockDim.x + threadIdx.x;
    if (i < nnz) atomicAdd(&counts[rows[i]], 1);
}

// exact exclusive scan over NN row counts -> offs[0..NN]
__global__ __launch_bounds__(1024) void scan_k(const int* __restrict__ counts,
                                               int* __restrict__ offs) {
    constexpr int CHUNK = (NN + 1023) / 1024;   // 147
    __shared__ int part[1024];
    int t = threadIdx.x;
    int b = t * CHUNK;
    int e = min(b + CHUNK, NN);
    int sum = 0;
    for (int i = b; i < e; ++i) sum += counts[i];
    part[t] = sum;
    __syncthreads();
    for (int d = 1; d < 1024; d <<= 1) {
        int v = (t >= d) ? part[t - d] : 0;
        __syncthreads();
        part[t] += v;
        __syncthreads();
    }
    int run = (t == 0) ? 0 : part[t - 1];
    for (int i = b; i < e; ++i) { offs[i] = run; run += counts[i]; }
    if (b < NN && e == NN) offs[NN] = run;
}

__global__ void gcur_k(const int* __restrict__ offs, int* __restrict__ gcur) {
    int b = blockIdx.x * blockDim.x + threadIdx.x;
    if (b < NBC) gcur[b] = offs[min(b * 256, NN)];
}

// pass A: block-local LDS counting sort of a 16K-edge chunk into 586 coarse
// buckets; destination-ordered emission -> fully coalesced global writes.
__global__ __launch_bounds__(1024) void passA_k(const int* __restrict__ rows,
                                                const int* __restrict__ cols,
                                                const float* __restrict__ vals,
                                                int* __restrict__ gcur,
                                                int2* __restrict__ stage, int nnz) {
    __shared__ int lhist[NBC];
    __shared__ int loff[NBC];
    __shared__ int gbase[NBC];
    __shared__ int lcur[NBC];
    __shared__ int part[1024];
    __shared__ unsigned short inv[CHUNK_E];
    int t = threadIdx.x;
    int cb = blockIdx.x * CHUNK_E;
    int ce = min(cb + CHUNK_E, nnz);
    // phase 1: histogram
    for (int i = t; i < NBC; i += 1024) lhist[i] = 0;
    __syncthreads();
    for (int i = cb + t; i < ce; i += 1024) atomicAdd(&lhist[rows[i] >> 8], 1);
    __syncthreads();
    // phase 2: scan + reserve global ranges
    part[t] = (t < NBC) ? lhist[t] : 0;
    __syncthreads();
    for (int d = 1; d < 1024; d <<= 1) {
        int v = (t >= d) ? part[t - d] : 0;
        __syncthreads();
        part[t] += v;
        __syncthreads();
    }
    if (t < NBC) {
        int cnt = lhist[t];
        int lo = part[t] - cnt;
        loff[t] = lo;
        lcur[t] = lo;
        gbase[t] = cnt ? atomicAdd(&gcur[t], cnt) : 0;
    }
    __syncthreads();
    // phase 3: rank (inverse permutation)
    for (int i = cb + t; i < ce; i += 1024) {
        int d = atomicAdd(&lcur[rows[i] >> 8], 1);
        inv[d] = (unsigned short)(i - cb);
    }
    __syncthreads();
    // phase 4: destination-ordered emit (coalesced)
    int n = ce - cb;
    for (int dst = t; dst < n; dst += 1024) {
        int i = cb + inv[dst];
        int r = rows[i];
        int bk = r >> 8;
        int pos = gbase[bk] + dst - loff[bk];
        stage[pos] = make_int2(cols[i] | ((r & 255) << 18), __float_as_int(vals[i]));
    }
}

// pass B: per coarse bucket, scatter to exact CSR row positions (L2-hot window)
__global__ __launch_bounds__(256) void passB_k(const int2* __restrict__ stage,
                                               const int* __restrict__ offs,
                                               int2* __restrict__ edges) {
    __shared__ int rcur[256];
    int b = blockIdx.x;
    int t = threadIdx.x;
    rcur[t] = offs[min(b * 256 + t, NN)];
    __syncthreads();
    int beg = offs[min(b * 256, NN)];
    int end = offs[min(b * 256 + 256, NN)];
    for (int i = beg + t; i < end; i += 256) {
        int2 e = stage[i];
        int lrow = (e.x >> 18) & 255;
        int pos = atomicAdd(&rcur[lrow], 1);
        edges[pos] = make_int2(e.x & 0x3ffff, e.y);
    }
}

// ======================= init: acc = emb (f32), hb0 = bf16(emb) =======================
__global__ void init_k(const float4* __restrict__ ue, const float4* __restrict__ ie,
                       float4* __restrict__ acc, uint2* __restrict__ hb0) {
    int i = blockIdx.x * blockDim.x + threadIdx.x;
    const int n4 = (int)(N64 / 4);
    if (i >= n4) return;
    const int u4 = (int)(U64 / 4);
    float4 v = (i < u4) ? ue[i] : ie[i - u4];
    acc[i] = v;
    hb0[i] = make_uint2(bfp(v.x, v.y), bfp(v.z, v.w));
}

// ======================= CSR row-gather SpMM (bf16 x) =======================
// One wave per row; 4 groups x 16 lanes; lane holds 4 dims; 32 edges in flight.
// MODE 1: yb = bf16(A*x); acc += A*x
// MODE 2: acc = (acc + A*x) * 0.25
template<int MODE>
__global__ __launch_bounds__(256) void spmm_g(
    const int* __restrict__ offs, const int2* __restrict__ edges,
    const unsigned int* __restrict__ xb,
    uint2* __restrict__ yb, float4* __restrict__ acc) {
    int w = (blockIdx.x * 256 + (int)threadIdx.x) >> 6;
    int lane = threadIdx.x & 63;
    if (w >= NN) return;
    int beg = offs[w], end = offs[w + 1];
    int g = lane >> 4, gl = lane & 15;
    float4 s = make_float4(0.f, 0.f, 0.f, 0.f);
    for (int p = beg; p < end; p += 32) {
        int idx = p + lane;
        int2 e = (lane < 32 && idx < end) ? edges[idx] : make_int2(0, 0);
        #pragma unroll
        for (int j = 0; j < 8; ++j) {
            int src = g * 8 + j;
            int c = __shfl(e.x, src);
            float v = __int_as_float(__shfl(e.y, src));
            uint2 u = *(const uint2*)(xb + (size_t)c * 32 + gl * 2);
            float x0 = __uint_as_float(u.x << 16);
            float x1 = __uint_as_float(u.x & 0xffff0000u);
            float x2 = __uint_as_float(u.y << 16);
            float x3 = __uint_as_float(u.y & 0xffff0000u);
            s.x += v * x0; s.y += v * x1; s.z += v * x2; s.w += v * x3;
        }
    }
    #pragma unroll
    for (int d = 16; d <= 32; d <<= 1) {
        s.x += __shfl_xor(s.x, d);
        s.y += __shfl_xor(s.y, d);
        s.z += __shfl_xor(s.z, d);
        s.w += __shfl_xor(s.w, d);
    }
    if (lane < 16) {
        size_t o = (size_t)w * 16 + gl;
        if (MODE == 1) {
            yb[o] = make_uint2(bfp(s.x, s.y), bfp(s.z, s.w));
            float4 a = acc[o];
            acc[o] = make_float4(a.x + s.x, a.y + s.y, a.z + s.z, a.w + s.w);
        } else {
            float4 a = acc[o];
            acc[o] = make_float4((a.x + s.x) * 0.25f, (a.y + s.y) * 0.25f,
                                 (a.z + s.z) * 0.25f, (a.w + s.w) * 0.25f);
        }
    }
}

// ======================= epilogue =======================

__global__ void epi_k(const float4* __restrict__ comb, const float4* __restrict__ mask,
                      float4* __restrict__ masked, float4* __restrict__ mout) {
    int i = blockIdx.x * blockDim.x + threadIdx.x;
    const int u4 = (int)(U64 / 4);
    if (i >= u4) return;
    float4 c = comb[i], m = mask[i];
    masked[i] = make_float4(c.x * m.x, c.y * m.y, c.z * m.z, c.w * m.w);
    mout[i] = m;
}

__global__ __launch_bounds__(256) void attr_gemm_k(const float* __restrict__ masked,
                                                   const float* __restrict__ W,
                                                   const float* __restrict__ b,
                                                   float* __restrict__ out) {
    __shared__ float Wl[64 * 64];
    __shared__ float bl[64];
    int t = threadIdx.x;
    #pragma unroll
    for (int k = 0; k < 16; ++k) Wl[t + 256 * k] = W[t + 256 * k];
    if (t < 64) bl[t] = b[t];
    __syncthreads();
    int wave = t >> 6, lane = t & 63;
    int row = blockIdx.x * 4 + wave;
    if (row >= NU) return;
    float mval = masked[(size_t)row * EMB + lane];
    float sum = bl[lane];
    #pragma unroll
    for (int k = 0; k < 64; ++k) {
        sum += __shfl(mval, k) * Wl[k * 64 + lane];
    }
    out[(size_t)row * EMB + lane] = fmaxf(sum, 0.f);
}

// ======================= fallback (atomic path) =======================

__global__ void finit_k(const float4* __restrict__ ue, const float4* __restrict__ ie,
                        float4* __restrict__ acc, float4* __restrict__ h0,
                        float4* __restrict__ h1) {
    int i = blockIdx.x * blockDim.x + threadIdx.x;
    const int n4 = (int)(N64 / 4);
    if (i >= n4) return;
    const int u4 = (int)(U64 / 4);
    float4 v = (i < u4) ? ue[i] : ie[i - u4];
    acc[i] = v; h0[i] = v; h1[i] = make_float4(0.f, 0.f, 0.f, 0.f);
}

__global__ void spmm_atomic_k(const int* __restrict__ rows, const int* __restrict__ cols,
                              const float* __restrict__ vals,
                              const float* __restrict__ x, float* __restrict__ y, int nnz) {
    int e = (blockIdx.x * blockDim.x + threadIdx.x) >> 6;
    int lane = threadIdx.x & 63;
    if (e >= nnz) return;
    int r = rows[e]; int c = cols[e]; float v = vals[e];
    atomicAdd(&y[(size_t)r * EMB + lane], x[(size_t)c * EMB + lane] * v);
}

__global__ void addzero_k(float4* __restrict__ acc, const float4* __restrict__ hin,
                          float4* __restrict__ hz) {
    int i = blockIdx.x * blockDim.x + threadIdx.x;
    const int n4 = (int)(N64 / 4);
    if (i >= n4) return;
    float4 a = acc[i]; float4 b = hin[i];
    a.x += b.x; a.y += b.y; a.z += b.z; a.w += b.w;
    acc[i] = a; hz[i] = make_float4(0.f, 0.f, 0.f, 0.f);
}

__global__ void final_k(float4* __restrict__ acc_io, const float4* __restrict__ hlast,
                        const float4* __restrict__ mask, float4* __restrict__ masked_out) {
    int i = blockIdx.x * blockDim.x + threadIdx.x;
    const int n4 = (int)(N64 / 4);
    if (i >= n4) return;
    float4 a = acc_io[i]; float4 h = hlast[i];
    float4 c = make_float4((a.x + h.x) * 0.25f, (a.y + h.y) * 0.25f,
                           (a.z + h.z) * 0.25f, (a.w + h.w) * 0.25f);
    acc_io[i] = c;
    const int u4 = (int)(U64 / 4);
    if (i < u4) {
        float4 m = mask[i];
        masked_out[i] = make_float4(c.x * m.x, c.y * m.y, c.z * m.z, c.w * m.w);
    }
}

__global__ void copy_k(const float4* __restrict__ src, float4* __restrict__ dst, int n4) {
    int i = blockIdx.x * blockDim.x + threadIdx.x;
    if (i < n4) dst[i] = src[i];
}

// ======================= launch =======================

extern "C" void kernel_launch(void* const* d_in, const int* in_sizes, int n_in,
                              void* d_out, int out_size, void* d_ws, size_t ws_size,
                              hipStream_t stream) {
    const float* user_emb = (const float*)d_in[0];
    const float* item_emb = (const float*)d_in[1];
    const int*   rows     = (const int*)d_in[2];
    const int*   cols     = (const int*)d_in[3];
    const float* vals     = (const float*)d_in[4];
    const float* mask     = (const float*)d_in[5];
    const float* W        = (const float*)d_in[6];
    const float* b        = (const float*)d_in[7];
    float* out = (float*)d_out;
    const int nnz = in_sizes[2];

    float* acc = out;                         // -> user_final || item_final
    float* masked_out = out + N64;
    float* pred_out   = out + N64 + U64;
    float* mask_out   = out + N64 + 2 * U64;

    const int blk = 256;
    const int n4 = (int)(N64 / 4);
    const int grid_n4 = (n4 + blk - 1) / blk;
    const int u4 = (int)(U64 / 4);

    // ws carve: counts | offs | gcur | edges
    const size_t CNT = 150016;                // >= NN+1
    int* counts = (int*)d_ws;
    int* offs   = counts + CNT;
    int* gcur   = offs + CNT;
    int2* edges = (int2*)(gcur + 640);
    const size_t need = (CNT * 2 + 640) * 4 + (size_t)nnz * 8 + 64;

    if (ws_size >= need) {
        // stage lives in d_out's h-region (dead until init_k)
        int2* stage = (int2*)(out + N64);
        uint2* hb0 = (uint2*)(out + N64);                 // 19.2 MB
        uint2* hb1 = hb0 + (N64 / 4);

        zero_k<<<(int)((CNT / 4 + blk - 1) / blk), blk, 0, stream>>>((int4*)counts,
                                                                     (int)(CNT / 4));
        hist_k<<<(nnz + blk - 1) / blk, blk, 0, stream>>>(rows, counts, nnz);
        scan_k<<<1, 1024, 0, stream>>>(counts, offs);
        gcur_k<<<(NBC + blk - 1) / blk, blk, 0, stream>>>(offs, gcur);
        passA_k<<<(nnz + CHUNK_E - 1) / CHUNK_E, 1024, 0, stream>>>(rows, cols, vals,
                                                                    gcur, stage, nnz);
        passB_k<<<NBC, blk, 0, stream>>>(stage, offs, edges);

        init_k<<<grid_n4, blk, 0, stream>>>((const float4*)user_emb,
                                            (const float4*)item_emb,
                                            (float4*)acc, (uint2*)hb0);

        const int grid_sp = (int)(((size_t)NN * 64) / blk);   // 37500
        spmm_g<1><<<grid_sp, blk, 0, stream>>>(offs, edges, (const unsigned int*)hb0,
                                               hb1, (float4*)acc);
        spmm_g<1><<<grid_sp, blk, 0, stream>>>(offs, edges, (const unsigned int*)hb1,
                                               hb0, (float4*)acc);
        spmm_g<2><<<grid_sp, blk, 0, stream>>>(offs, edges, (const unsigned int*)hb0,
                                               nullptr, (float4*)acc);

        epi_k<<<(u4 + blk - 1) / blk, blk, 0, stream>>>((const float4*)acc,
            (const float4*)mask, (float4*)masked_out, (float4*)mask_out);
        attr_gemm_k<<<NU / 4, blk, 0, stream>>>(masked_out, W, b, pred_out);
    } else {
        // fallback: atomic scatter path entirely in d_out
        float* h0 = out + N64;
        float* h1 = out + 2 * N64;
        finit_k<<<grid_n4, blk, 0, stream>>>((const float4*)user_emb,
                                             (const float4*)item_emb,
                                             (float4*)acc, (float4*)h0, (float4*)h1);
        const long long st = (long long)nnz * 64;
        const int grid_sc = (int)((st + blk - 1) / blk);
        spmm_atomic_k<<<grid_sc, blk, 0, stream>>>(rows, cols, vals, h0, h1, nnz);
        addzero_k<<<grid_n4, blk, 0, stream>>>((float4*)acc, (const float4*)h1, (float4*)h0);
        spmm_atomic_k<<<grid_sc, blk, 0, stream>>>(rows, cols, vals, h1, h0, nnz);
        addzero_k<<<grid_n4, blk, 0, stream>>>((float4*)acc, (const float4*)h0, (float4*)h1);
        spmm_atomic_k<<<grid_sc, blk, 0, stream>>>(rows, cols, vals, h0, h1, nnz);
        final_k<<<grid_n4, blk, 0, stream>>>((float4*)acc, (const float4*)h1,
                                             (const float4*)mask, (float4*)masked_out);
        attr_gemm_k<<<NU / 4, blk, 0, stream>>>(masked_out, W, b, pred_out);
        copy_k<<<(u4 + blk - 1) / blk, blk, 0, stream>>>((const float4*)mask,
                                                         (float4*)mask_out, u4);
    }
}

// Round 5
// 841.499 us; speedup vs baseline: 3.9119x; 1.2021x over previous
//
#include <hip/hip_runtime.h>

constexpr int NU = 100000;
constexpr int NI = 50000;
constexpr int NN = 150000;
constexpr int EMB = 64;
constexpr size_t U64 = (size_t)NU * EMB;   // 6,400,000
constexpr size_t N64 = (size_t)NN * EMB;   // 9,600,000
constexpr int NBC = (NN + 255) >> 8;       // 586 coarse buckets of 256 rows
constexpr int CHUNK_E = 16384;             // edges per sort block
constexpr int NSB = (NN + 1023) / 1024;    // 147 scan blocks

// ---------- bf16 pack (RNE) ----------
__device__ inline unsigned int bfp(float a, float b) {
    unsigned int ua = __float_as_uint(a), ub = __float_as_uint(b);
    ua += 0x7fffu + ((ua >> 16) & 1u);
    ub += 0x7fffu + ((ub >> 16) & 1u);
    return (ua >> 16) | (ub & 0xffff0000u);
}

// ======================= CSR build =======================

__global__ void zero_k(int4* __restrict__ p, int n) {
    int i = blockIdx.x * blockDim.x + threadIdx.x;
    if (i < n) p[i] = make_int4(0, 0, 0, 0);
}

__global__ void hist_k(const int* __restrict__ rows, int* __restrict__ counts, int nnz) {
    int i = blockIdx.x * blockDim.x + threadIdx.x;
    if (i < nnz) atomicAdd(&counts[rows[i]], 1);
}

// hierarchical scan: (1) per-block LDS scan, (2) scan of block sums, (3) add
__global__ __launch_bounds__(1024) void scan1_k(const int* __restrict__ counts,
                                                int* __restrict__ offs,
                                                int* __restrict__ bsum) {
    __shared__ int part[1024];
    int t = threadIdx.x;
    int i = blockIdx.x * 1024 + t;
    int v = (i < NN) ? counts[i] : 0;
    part[t] = v;
    __syncthreads();
    for (int d = 1; d < 1024; d <<= 1) {
        int u = (t >= d) ? part[t - d] : 0;
        __syncthreads();
        part[t] += u;
        __syncthreads();
    }
    if (i < NN) offs[i] = part[t] - v;           // exclusive within block
    if (t == 1023) bsum[blockIdx.x] = part[1023];
}

__global__ __launch_bounds__(256) void scan2_k(const int* __restrict__ bsum,
                                               int* __restrict__ bscan) {
    __shared__ int part[256];
    int t = threadIdx.x;
    int v = (t < NSB) ? bsum[t] : 0;
    part[t] = v;
    __syncthreads();
    for (int d = 1; d < 256; d <<= 1) {
        int u = (t >= d) ? part[t - d] : 0;
        __syncthreads();
        part[t] += u;
        __syncthreads();
    }
    if (t < NSB) bscan[t] = part[t] - v;         // exclusive block prefix
}

__global__ __launch_bounds__(1024) void scan3_k(int* __restrict__ offs,
                                                const int* __restrict__ bscan, int nnz) {
    int i = blockIdx.x * 1024 + threadIdx.x;
    if (i < NN) offs[i] += bscan[blockIdx.x];
    if (i == 0) offs[NN] = nnz;
}

__global__ void gcur_k(const int* __restrict__ offs, int* __restrict__ gcur) {
    int b = blockIdx.x * blockDim.x + threadIdx.x;
    if (b < NBC) gcur[b] = offs[min(b * 256, NN)];
}

// pass A: block-local LDS counting sort of a 16K-edge chunk into 586 coarse
// buckets; destination-ordered emission -> fully coalesced global writes.
__global__ __launch_bounds__(1024) void passA_k(const int* __restrict__ rows,
                                                const int* __restrict__ cols,
                                                const float* __restrict__ vals,
                                                int* __restrict__ gcur,
                                                int2* __restrict__ stage, int nnz) {
    __shared__ int lhist[NBC];
    __shared__ int loff[NBC];
    __shared__ int gbase[NBC];
    __shared__ int lcur[NBC];
    __shared__ int part[1024];
    __shared__ unsigned short inv[CHUNK_E];
    int t = threadIdx.x;
    int cb = blockIdx.x * CHUNK_E;
    int ce = min(cb + CHUNK_E, nnz);
    for (int i = t; i < NBC; i += 1024) lhist[i] = 0;
    __syncthreads();
    for (int i = cb + t; i < ce; i += 1024) atomicAdd(&lhist[rows[i] >> 8], 1);
    __syncthreads();
    part[t] = (t < NBC) ? lhist[t] : 0;
    __syncthreads();
    for (int d = 1; d < 1024; d <<= 1) {
        int v = (t >= d) ? part[t - d] : 0;
        __syncthreads();
        part[t] += v;
        __syncthreads();
    }
    if (t < NBC) {
        int cnt = lhist[t];
        int lo = part[t] - cnt;
        loff[t] = lo;
        lcur[t] = lo;
        gbase[t] = cnt ? atomicAdd(&gcur[t], cnt) : 0;
    }
    __syncthreads();
    for (int i = cb + t; i < ce; i += 1024) {
        int d = atomicAdd(&lcur[rows[i] >> 8], 1);
        inv[d] = (unsigned short)(i - cb);
    }
    __syncthreads();
    int n = ce - cb;
    for (int dst = t; dst < n; dst += 1024) {
        int i = cb + inv[dst];
        int r = rows[i];
        int bk = r >> 8;
        int pos = gbase[bk] + dst - loff[bk];
        stage[pos] = make_int2(cols[i] | ((r & 255) << 18), __float_as_int(vals[i]));
    }
}

// pass B: per coarse bucket, scatter to exact CSR row positions (L2-hot window)
__global__ __launch_bounds__(256) void passB_k(const int2* __restrict__ stage,
                                               const int* __restrict__ offs,
                                               int2* __restrict__ edges) {
    __shared__ int rcur[256];
    int b = blockIdx.x;
    int t = threadIdx.x;
    rcur[t] = offs[min(b * 256 + t, NN)];
    __syncthreads();
    int beg = offs[min(b * 256, NN)];
    int end = offs[min(b * 256 + 256, NN)];
    for (int i = beg + t; i < end; i += 256) {
        int2 e = stage[i];
        int lrow = (e.x >> 18) & 255;
        int pos = atomicAdd(&rcur[lrow], 1);
        edges[pos] = make_int2(e.x & 0x3ffff, e.y);
    }
}

// ======================= init: acc = emb (f32), hb0 = bf16(emb) =======================
__global__ void init_k(const float4* __restrict__ ue, const float4* __restrict__ ie,
                       float4* __restrict__ acc, uint2* __restrict__ hb0) {
    int i = blockIdx.x * blockDim.x + threadIdx.x;
    const int n4 = (int)(N64 / 4);
    if (i >= n4) return;
    const int u4 = (int)(U64 / 4);
    float4 v = (i < u4) ? ue[i] : ie[i - u4];
    acc[i] = v;
    hb0[i] = make_uint2(bfp(v.x, v.y), bfp(v.z, v.w));
}

// ======================= CSR row-gather SpMM (bf16 x) =======================
template<int MODE>
__global__ __launch_bounds__(256) void spmm_g(
    const int* __restrict__ offs, const int2* __restrict__ edges,
    const unsigned int* __restrict__ xb,
    uint2* __restrict__ yb, float4* __restrict__ acc) {
    int w = (blockIdx.x * 256 + (int)threadIdx.x) >> 6;
    int lane = threadIdx.x & 63;
    if (w >= NN) return;
    int beg = offs[w], end = offs[w + 1];
    int g = lane >> 4, gl = lane & 15;
    float4 s = make_float4(0.f, 0.f, 0.f, 0.f);
    for (int p = beg; p < end; p += 32) {
        int idx = p + lane;
        int2 e = (lane < 32 && idx < end) ? edges[idx] : make_int2(0, 0);
        #pragma unroll
        for (int j = 0; j < 8; ++j) {
            int src = g * 8 + j;
            int c = __shfl(e.x, src);
            float v = __int_as_float(__shfl(e.y, src));
            uint2 u = *(const uint2*)(xb + (size_t)c * 32 + gl * 2);
            float x0 = __uint_as_float(u.x << 16);
            float x1 = __uint_as_float(u.x & 0xffff0000u);
            float x2 = __uint_as_float(u.y << 16);
            float x3 = __uint_as_float(u.y & 0xffff0000u);
            s.x += v * x0; s.y += v * x1; s.z += v * x2; s.w += v * x3;
        }
    }
    #pragma unroll
    for (int d = 16; d <= 32; d <<= 1) {
        s.x += __shfl_xor(s.x, d);
        s.y += __shfl_xor(s.y, d);
        s.z += __shfl_xor(s.z, d);
        s.w += __shfl_xor(s.w, d);
    }
    if (lane < 16) {
        size_t o = (size_t)w * 16 + gl;
        if (MODE == 1) {
            yb[o] = make_uint2(bfp(s.x, s.y), bfp(s.z, s.w));
            float4 a = acc[o];
            acc[o] = make_float4(a.x + s.x, a.y + s.y, a.z + s.z, a.w + s.w);
        } else {
            float4 a = acc[o];
            acc[o] = make_float4((a.x + s.x) * 0.25f, (a.y + s.y) * 0.25f,
                                 (a.z + s.z) * 0.25f, (a.w + s.w) * 0.25f);
        }
    }
}

// ======================= epilogue =======================

__global__ void epi_k(const float4* __restrict__ comb, const float4* __restrict__ mask,
                      float4* __restrict__ masked, float4* __restrict__ mout) {
    int i = blockIdx.x * blockDim.x + threadIdx.x;
    const int u4 = (int)(U64 / 4);
    if (i >= u4) return;
    float4 c = comb[i], m = mask[i];
    masked[i] = make_float4(c.x * m.x, c.y * m.y, c.z * m.z, c.w * m.w);
    mout[i] = m;
}

__global__ __launch_bounds__(256) void attr_gemm_k(const float* __restrict__ masked,
                                                   const float* __restrict__ W,
                                                   const float* __restrict__ b,
                                                   float* __restrict__ out) {
    __shared__ float Wl[64 * 64];
    __shared__ float bl[64];
    int t = threadIdx.x;
    #pragma unroll
    for (int k = 0; k < 16; ++k) Wl[t + 256 * k] = W[t + 256 * k];
    if (t < 64) bl[t] = b[t];
    __syncthreads();
    int wave = t >> 6, lane = t & 63;
    int row = blockIdx.x * 4 + wave;
    if (row >= NU) return;
    float mval = masked[(size_t)row * EMB + lane];
    float sum = bl[lane];
    #pragma unroll
    for (int k = 0; k < 64; ++k) {
        sum += __shfl(mval, k) * Wl[k * 64 + lane];
    }
    out[(size_t)row * EMB + lane] = fmaxf(sum, 0.f);
}

// ======================= fallback (atomic path) =======================

__global__ void finit_k(const float4* __restrict__ ue, const float4* __restrict__ ie,
                        float4* __restrict__ acc, float4* __restrict__ h0,
                        float4* __restrict__ h1) {
    int i = blockIdx.x * blockDim.x + threadIdx.x;
    const int n4 = (int)(N64 / 4);
    if (i >= n4) return;
    const int u4 = (int)(U64 / 4);
    float4 v = (i < u4) ? ue[i] : ie[i - u4];
    acc[i] = v; h0[i] = v; h1[i] = make_float4(0.f, 0.f, 0.f, 0.f);
}

__global__ void spmm_atomic_k(const int* __restrict__ rows, const int* __restrict__ cols,
                              const float* __restrict__ vals,
                              const float* __restrict__ x, float* __restrict__ y, int nnz) {
    int e = (blockIdx.x * blockDim.x + threadIdx.x) >> 6;
    int lane = threadIdx.x & 63;
    if (e >= nnz) return;
    int r = rows[e]; int c = cols[e]; float v = vals[e];
    atomicAdd(&y[(size_t)r * EMB + lane], x[(size_t)c * EMB + lane] * v);
}

__global__ void addzero_k(float4* __restrict__ acc, const float4* __restrict__ hin,
                          float4* __restrict__ hz) {
    int i = blockIdx.x * blockDim.x + threadIdx.x;
    const int n4 = (int)(N64 / 4);
    if (i >= n4) return;
    float4 a = acc[i]; float4 b = hin[i];
    a.x += b.x; a.y += b.y; a.z += b.z; a.w += b.w;
    acc[i] = a; hz[i] = make_float4(0.f, 0.f, 0.f, 0.f);
}

__global__ void final_k(float4* __restrict__ acc_io, const float4* __restrict__ hlast,
                        const float4* __restrict__ mask, float4* __restrict__ masked_out) {
    int i = blockIdx.x * blockDim.x + threadIdx.x;
    const int n4 = (int)(N64 / 4);
    if (i >= n4) return;
    float4 a = acc_io[i]; float4 h = hlast[i];
    float4 c = make_float4((a.x + h.x) * 0.25f, (a.y + h.y) * 0.25f,
                           (a.z + h.z) * 0.25f, (a.w + h.w) * 0.25f);
    acc_io[i] = c;
    const int u4 = (int)(U64 / 4);
    if (i < u4) {
        float4 m = mask[i];
        masked_out[i] = make_float4(c.x * m.x, c.y * m.y, c.z * m.z, c.w * m.w);
    }
}

__global__ void copy_k(const float4* __restrict__ src, float4* __restrict__ dst, int n4) {
    int i = blockIdx.x * blockDim.x + threadIdx.x;
    if (i < n4) dst[i] = src[i];
}

// ======================= launch =======================

extern "C" void kernel_launch(void* const* d_in, const int* in_sizes, int n_in,
                              void* d_out, int out_size, void* d_ws, size_t ws_size,
                              hipStream_t stream) {
    const float* user_emb = (const float*)d_in[0];
    const float* item_emb = (const float*)d_in[1];
    const int*   rows     = (const int*)d_in[2];
    const int*   cols     = (const int*)d_in[3];
    const float* vals     = (const float*)d_in[4];
    const float* mask     = (const float*)d_in[5];
    const float* W        = (const float*)d_in[6];
    const float* b        = (const float*)d_in[7];
    float* out = (float*)d_out;
    const int nnz = in_sizes[2];

    float* acc = out;                         // -> user_final || item_final
    float* masked_out = out + N64;
    float* pred_out   = out + N64 + U64;
    float* mask_out   = out + N64 + 2 * U64;

    const int blk = 256;
    const int n4 = (int)(N64 / 4);
    const int grid_n4 = (n4 + blk - 1) / blk;
    const int u4 = (int)(U64 / 4);

    // ws carve: counts | offs | gcur | bsum | bscan | edges
    const size_t CNT = 150016;                // >= NN+1
    int* counts = (int*)d_ws;
    int* offs   = counts + CNT;
    int* gcur   = offs + CNT;
    int* bsum   = gcur + 640;
    int* bscan  = bsum + 256;
    int2* edges = (int2*)(bscan + 256);
    const size_t need = (CNT * 2 + 640 + 512) * 4 + (size_t)nnz * 8 + 64;

    if (ws_size >= need) {
        // stage lives in d_out's h-region (dead until init_k)
        int2* stage = (int2*)(out + N64);
        uint2* hb0 = (uint2*)(out + N64);                 // 19.2 MB
        uint2* hb1 = hb0 + (N64 / 4);

        zero_k<<<(int)((CNT / 4 + blk - 1) / blk), blk, 0, stream>>>((int4*)counts,
                                                                     (int)(CNT / 4));
        hist_k<<<(nnz + blk - 1) / blk, blk, 0, stream>>>(rows, counts, nnz);
        scan1_k<<<NSB, 1024, 0, stream>>>(counts, offs, bsum);
        scan2_k<<<1, 256, 0, stream>>>(bsum, bscan);
        scan3_k<<<NSB, 1024, 0, stream>>>(offs, bscan, nnz);
        gcur_k<<<(NBC + blk - 1) / blk, blk, 0, stream>>>(offs, gcur);
        passA_k<<<(nnz + CHUNK_E - 1) / CHUNK_E, 1024, 0, stream>>>(rows, cols, vals,
                                                                    gcur, stage, nnz);
        passB_k<<<NBC, blk, 0, stream>>>(stage, offs, edges);

        init_k<<<grid_n4, blk, 0, stream>>>((const float4*)user_emb,
                                            (const float4*)item_emb,
                                            (float4*)acc, (uint2*)hb0);

        const int grid_sp = (int)(((size_t)NN * 64) / blk);   // 37500
        spmm_g<1><<<grid_sp, blk, 0, stream>>>(offs, edges, (const unsigned int*)hb0,
                                               hb1, (float4*)acc);
        spmm_g<1><<<grid_sp, blk, 0, stream>>>(offs, edges, (const unsigned int*)hb1,
                                               hb0, (float4*)acc);
        spmm_g<2><<<grid_sp, blk, 0, stream>>>(offs, edges, (const unsigned int*)hb0,
                                               nullptr, (float4*)acc);

        epi_k<<<(u4 + blk - 1) / blk, blk, 0, stream>>>((const float4*)acc,
            (const float4*)mask, (float4*)masked_out, (float4*)mask_out);
        attr_gemm_k<<<NU / 4, blk, 0, stream>>>(masked_out, W, b, pred_out);
    } else {
        // fallback: atomic scatter path entirely in d_out
        float* h0 = out + N64;
        float* h1 = out + 2 * N64;
        finit_k<<<grid_n4, blk, 0, stream>>>((const float4*)user_emb,
                                             (const float4*)item_emb,
                                             (float4*)acc, (float4*)h0, (float4*)h1);
        const long long st = (long long)nnz * 64;
        const int grid_sc = (int)((st + blk - 1) / blk);
        spmm_atomic_k<<<grid_sc, blk, 0, stream>>>(rows, cols, vals, h0, h1, nnz);
        addzero_k<<<grid_n4, blk, 0, stream>>>((float4*)acc, (const float4*)h1, (float4*)h0);
        spmm_atomic_k<<<grid_sc, blk, 0, stream>>>(rows, cols, vals, h1, h0, nnz);
        addzero_k<<<grid_n4, blk, 0, stream>>>((float4*)acc, (const float4*)h0, (float4*)h1);
        spmm_atomic_k<<<grid_sc, blk, 0, stream>>>(rows, cols, vals, h0, h1, nnz);
        final_k<<<grid_n4, blk, 0, stream>>>((float4*)acc, (const float4*)h1,
                                             (const float4*)mask, (float4*)masked_out);
        attr_gemm_k<<<NU / 4, blk, 0, stream>>>(masked_out, W, b, pred_out);
        copy_k<<<(u4 + blk - 1) / blk, blk, 0, stream>>>((const float4*)mask,
                                                         (float4*)mask_out, u4);
    }
}

// Round 6
// 612.588 us; speedup vs baseline: 5.3736x; 1.3737x over previous
//
#include <hip/hip_runtime.h>

constexpr int NU = 100000;
constexpr int NI = 50000;
constexpr int NN = 150000;
constexpr int EMB = 64;
constexpr size_t U64 = (size_t)NU * EMB;   // 6,400,000
constexpr size_t N64 = (size_t)NN * EMB;   // 9,600,000
constexpr int NBC = (NN + 255) >> 8;       // 586 coarse buckets of 256 rows
constexpr int CHUNK_E = 16384;             // edges per sort block

// ---------- bf16 pack (RNE) ----------
__device__ inline unsigned int bfp(float a, float b) {
    unsigned int ua = __float_as_uint(a), ub = __float_as_uint(b);
    ua += 0x7fffu + ((ua >> 16) & 1u);
    ub += 0x7fffu + ((ub >> 16) & 1u);
    return (ua >> 16) | (ub & 0xffff0000u);
}

// ======================= CSR build =======================

__global__ void zero_k(int4* __restrict__ p, int n) {
    int i = blockIdx.x * blockDim.x + threadIdx.x;
    if (i < n) p[i] = make_int4(0, 0, 0, 0);
}

// coarse bucket histogram via LDS (no per-edge global atomics)
__global__ __launch_bounds__(1024) void chist_k(const int* __restrict__ rows,
                                                int* __restrict__ bcnt, int nnz) {
    __shared__ int lh[NBC];
    int t = threadIdx.x;
    for (int i = t; i < NBC; i += 1024) lh[i] = 0;
    __syncthreads();
    int cb = blockIdx.x * CHUNK_E;
    int ce = min(cb + CHUNK_E, nnz);
    for (int i = cb + t; i < ce; i += 1024) atomicAdd(&lh[rows[i] >> 8], 1);
    __syncthreads();
    for (int i = t; i < NBC; i += 1024) {
        int v = lh[i];
        if (v) atomicAdd(&bcnt[i], v);
    }
}

// scan of 586 bucket counts -> bbase[0..NBC] (bbase[NBC]=nnz), init gcur
__global__ __launch_bounds__(1024) void bscan_k(const int* __restrict__ bcnt,
                                                int* __restrict__ bbase,
                                                int* __restrict__ gcur, int nnz) {
    __shared__ int part[1024];
    int t = threadIdx.x;
    int v = (t < NBC) ? bcnt[t] : 0;
    part[t] = v;
    __syncthreads();
    for (int d = 1; d < 1024; d <<= 1) {
        int u = (t >= d) ? part[t - d] : 0;
        __syncthreads();
        part[t] += u;
        __syncthreads();
    }
    if (t < NBC) {
        int e = part[t] - v;
        bbase[t] = e;
        gcur[t] = e;
    }
    if (t == 0) bbase[NBC] = nnz;
}

// pass A: block-local LDS counting sort of a 16K-edge chunk into 586 coarse
// buckets; destination-ordered emission -> fully coalesced global writes.
__global__ __launch_bounds__(1024) void passA_k(const int* __restrict__ rows,
                                                const int* __restrict__ cols,
                                                const float* __restrict__ vals,
                                                int* __restrict__ gcur,
                                                int2* __restrict__ stage, int nnz) {
    __shared__ int lhist[NBC];
    __shared__ int loff[NBC];
    __shared__ int gbase[NBC];
    __shared__ int lcur[NBC];
    __shared__ int part[1024];
    __shared__ unsigned short inv[CHUNK_E];
    int t = threadIdx.x;
    int cb = blockIdx.x * CHUNK_E;
    int ce = min(cb + CHUNK_E, nnz);
    for (int i = t; i < NBC; i += 1024) lhist[i] = 0;
    __syncthreads();
    for (int i = cb + t; i < ce; i += 1024) atomicAdd(&lhist[rows[i] >> 8], 1);
    __syncthreads();
    part[t] = (t < NBC) ? lhist[t] : 0;
    __syncthreads();
    for (int d = 1; d < 1024; d <<= 1) {
        int v = (t >= d) ? part[t - d] : 0;
        __syncthreads();
        part[t] += v;
        __syncthreads();
    }
    if (t < NBC) {
        int cnt = lhist[t];
        int lo = part[t] - cnt;
        loff[t] = lo;
        lcur[t] = lo;
        gbase[t] = cnt ? atomicAdd(&gcur[t], cnt) : 0;
    }
    __syncthreads();
    for (int i = cb + t; i < ce; i += 1024) {
        int d = atomicAdd(&lcur[rows[i] >> 8], 1);
        inv[d] = (unsigned short)(i - cb);
    }
    __syncthreads();
    int n = ce - cb;
    for (int dst = t; dst < n; dst += 1024) {
        int i = cb + inv[dst];
        int r = rows[i];
        int bk = r >> 8;
        int pos = gbase[bk] + dst - loff[bk];
        stage[pos] = make_int2(cols[i] | ((r & 255) << 18), __float_as_int(vals[i]));
    }
}

// pass B: per coarse bucket — build exact per-row offsets in LDS (writes offs,
// replacing the global 150K hist+scan) and scatter edges to CSR positions.
__global__ __launch_bounds__(256) void passB_k(const int2* __restrict__ stage,
                                               const int* __restrict__ bbase,
                                               int* __restrict__ offs,
                                               int2* __restrict__ edges) {
    __shared__ int part[256];
    __shared__ int lcur[256];
    int b = blockIdx.x;
    int t = threadIdx.x;
    int beg = bbase[b];
    int end = bbase[b + 1];
    part[t] = 0;
    lcur[t] = 0;
    __syncthreads();
    for (int i = beg + t; i < end; i += 256) {
        atomicAdd(&lcur[(stage[i].x >> 18) & 255], 1);
    }
    __syncthreads();
    int v = lcur[t];
    part[t] = v;
    __syncthreads();
    for (int d = 1; d < 256; d <<= 1) {
        int u = (t >= d) ? part[t - d] : 0;
        __syncthreads();
        part[t] += u;
        __syncthreads();
    }
    int rowoff = beg + part[t] - v;    // global CSR offset for row b*256+t
    lcur[t] = rowoff;
    int gi = b * 256 + t;
    offs[gi] = rowoff;                 // rows >= NN get rowoff == end; offs[NN]=nnz ok
    __syncthreads();
    for (int i = beg + t; i < end; i += 256) {
        int2 e = stage[i];
        int lrow = (e.x >> 18) & 255;
        int pos = atomicAdd(&lcur[lrow], 1);
        edges[pos] = make_int2(e.x & 0x3ffff, e.y);
    }
}

// ======================= init: acc = emb (f32), hb0 = bf16(emb) =======================
__global__ void init_k(const float4* __restrict__ ue, const float4* __restrict__ ie,
                       float4* __restrict__ acc, uint2* __restrict__ hb0) {
    int i = blockIdx.x * blockDim.x + threadIdx.x;
    const int n4 = (int)(N64 / 4);
    if (i >= n4) return;
    const int u4 = (int)(U64 / 4);
    float4 v = (i < u4) ? ue[i] : ie[i - u4];
    acc[i] = v;
    hb0[i] = make_uint2(bfp(v.x, v.y), bfp(v.z, v.w));
}

// ======================= CSR row-gather SpMM (bf16 x) =======================
template<int MODE>
__global__ __launch_bounds__(256) void spmm_g(
    const int* __restrict__ offs, const int2* __restrict__ edges,
    const unsigned int* __restrict__ xb,
    uint2* __restrict__ yb, float4* __restrict__ acc) {
    int w = (blockIdx.x * 256 + (int)threadIdx.x) >> 6;
    int lane = threadIdx.x & 63;
    if (w >= NN) return;
    int beg = offs[w], end = offs[w + 1];
    int g = lane >> 4, gl = lane & 15;
    float4 s = make_float4(0.f, 0.f, 0.f, 0.f);
    for (int p = beg; p < end; p += 32) {
        int idx = p + lane;
        int2 e = (lane < 32 && idx < end) ? edges[idx] : make_int2(0, 0);
        #pragma unroll
        for (int j = 0; j < 8; ++j) {
            int src = g * 8 + j;
            int c = __shfl(e.x, src);
            float v = __int_as_float(__shfl(e.y, src));
            uint2 u = *(const uint2*)(xb + (size_t)c * 32 + gl * 2);
            float x0 = __uint_as_float(u.x << 16);
            float x1 = __uint_as_float(u.x & 0xffff0000u);
            float x2 = __uint_as_float(u.y << 16);
            float x3 = __uint_as_float(u.y & 0xffff0000u);
            s.x += v * x0; s.y += v * x1; s.z += v * x2; s.w += v * x3;
        }
    }
    #pragma unroll
    for (int d = 16; d <= 32; d <<= 1) {
        s.x += __shfl_xor(s.x, d);
        s.y += __shfl_xor(s.y, d);
        s.z += __shfl_xor(s.z, d);
        s.w += __shfl_xor(s.w, d);
    }
    if (lane < 16) {
        size_t o = (size_t)w * 16 + gl;
        if (MODE == 1) {
            yb[o] = make_uint2(bfp(s.x, s.y), bfp(s.z, s.w));
            float4 a = acc[o];
            acc[o] = make_float4(a.x + s.x, a.y + s.y, a.z + s.z, a.w + s.w);
        } else {
            float4 a = acc[o];
            acc[o] = make_float4((a.x + s.x) * 0.25f, (a.y + s.y) * 0.25f,
                                 (a.z + s.z) * 0.25f, (a.w + s.w) * 0.25f);
        }
    }
}

// ======================= epilogue =======================

__global__ void epi_k(const float4* __restrict__ comb, const float4* __restrict__ mask,
                      float4* __restrict__ masked, float4* __restrict__ mout) {
    int i = blockIdx.x * blockDim.x + threadIdx.x;
    const int u4 = (int)(U64 / 4);
    if (i >= u4) return;
    float4 c = comb[i], m = mask[i];
    masked[i] = make_float4(c.x * m.x, c.y * m.y, c.z * m.z, c.w * m.w);
    mout[i] = m;
}

__global__ __launch_bounds__(256) void attr_gemm_k(const float* __restrict__ masked,
                                                   const float* __restrict__ W,
                                                   const float* __restrict__ b,
                                                   float* __restrict__ out) {
    __shared__ float Wl[64 * 64];
    __shared__ float bl[64];
    int t = threadIdx.x;
    #pragma unroll
    for (int k = 0; k < 16; ++k) Wl[t + 256 * k] = W[t + 256 * k];
    if (t < 64) bl[t] = b[t];
    __syncthreads();
    int wave = t >> 6, lane = t & 63;
    int row = blockIdx.x * 4 + wave;
    if (row >= NU) return;
    float mval = masked[(size_t)row * EMB + lane];
    float sum = bl[lane];
    #pragma unroll
    for (int k = 0; k < 64; ++k) {
        sum += __shfl(mval, k) * Wl[k * 64 + lane];
    }
    out[(size_t)row * EMB + lane] = fmaxf(sum, 0.f);
}

// ======================= fallback (atomic path) =======================

__global__ void finit_k(const float4* __restrict__ ue, const float4* __restrict__ ie,
                        float4* __restrict__ acc, float4* __restrict__ h0,
                        float4* __restrict__ h1) {
    int i = blockIdx.x * blockDim.x + threadIdx.x;
    const int n4 = (int)(N64 / 4);
    if (i >= n4) return;
    const int u4 = (int)(U64 / 4);
    float4 v = (i < u4) ? ue[i] : ie[i - u4];
    acc[i] = v; h0[i] = v; h1[i] = make_float4(0.f, 0.f, 0.f, 0.f);
}

__global__ void spmm_atomic_k(const int* __restrict__ rows, const int* __restrict__ cols,
                              const float* __restrict__ vals,
                              const float* __restrict__ x, float* __restrict__ y, int nnz) {
    int e = (blockIdx.x * blockDim.x + threadIdx.x) >> 6;
    int lane = threadIdx.x & 63;
    if (e >= nnz) return;
    int r = rows[e]; int c = cols[e]; float v = vals[e];
    atomicAdd(&y[(size_t)r * EMB + lane], x[(size_t)c * EMB + lane] * v);
}

__global__ void addzero_k(float4* __restrict__ acc, const float4* __restrict__ hin,
                          float4* __restrict__ hz) {
    int i = blockIdx.x * blockDim.x + threadIdx.x;
    const int n4 = (int)(N64 / 4);
    if (i >= n4) return;
    float4 a = acc[i]; float4 b = hin[i];
    a.x += b.x; a.y += b.y; a.z += b.z; a.w += b.w;
    acc[i] = a; hz[i] = make_float4(0.f, 0.f, 0.f, 0.f);
}

__global__ void final_k(float4* __restrict__ acc_io, const float4* __restrict__ hlast,
                        const float4* __restrict__ mask, float4* __restrict__ masked_out) {
    int i = blockIdx.x * blockDim.x + threadIdx.x;
    const int n4 = (int)(N64 / 4);
    if (i >= n4) return;
    float4 a = acc_io[i]; float4 h = hlast[i];
    float4 c = make_float4((a.x + h.x) * 0.25f, (a.y + h.y) * 0.25f,
                           (a.z + h.z) * 0.25f, (a.w + h.w) * 0.25f);
    acc_io[i] = c;
    const int u4 = (int)(U64 / 4);
    if (i < u4) {
        float4 m = mask[i];
        masked_out[i] = make_float4(c.x * m.x, c.y * m.y, c.z * m.z, c.w * m.w);
    }
}

__global__ void copy_k(const float4* __restrict__ src, float4* __restrict__ dst, int n4) {
    int i = blockIdx.x * blockDim.x + threadIdx.x;
    if (i < n4) dst[i] = src[i];
}

// ======================= launch =======================

extern "C" void kernel_launch(void* const* d_in, const int* in_sizes, int n_in,
                              void* d_out, int out_size, void* d_ws, size_t ws_size,
                              hipStream_t stream) {
    const float* user_emb = (const float*)d_in[0];
    const float* item_emb = (const float*)d_in[1];
    const int*   rows     = (const int*)d_in[2];
    const int*   cols     = (const int*)d_in[3];
    const float* vals     = (const float*)d_in[4];
    const float* mask     = (const float*)d_in[5];
    const float* W        = (const float*)d_in[6];
    const float* b        = (const float*)d_in[7];
    float* out = (float*)d_out;
    const int nnz = in_sizes[2];

    float* acc = out;                         // -> user_final || item_final
    float* masked_out = out + N64;
    float* pred_out   = out + N64 + U64;
    float* mask_out   = out + N64 + 2 * U64;

    const int blk = 256;
    const int n4 = (int)(N64 / 4);
    const int grid_n4 = (n4 + blk - 1) / blk;
    const int u4 = (int)(U64 / 4);

    // ws carve: bcnt | bbase | gcur | offs | edges
    int* bcnt  = (int*)d_ws;                  // 640
    int* bbase = bcnt + 640;                  // 640 (NBC+1 used)
    int* gcur  = bbase + 640;                 // 640
    int* offs  = gcur + 640;                  // 150016 (NBC*256 = 150016 written)
    int2* edges = (int2*)(offs + 150016);
    const size_t need = (640 * 3 + 150016) * 4 + (size_t)nnz * 8 + 64;

    if (ws_size >= need) {
        // stage lives in d_out's h-region (dead until init_k)
        int2* stage = (int2*)(out + N64);
        uint2* hb0 = (uint2*)(out + N64);                 // 19.2 MB
        uint2* hb1 = hb0 + (N64 / 4);

        const int nblkA = (nnz + CHUNK_E - 1) / CHUNK_E;
        zero_k<<<1, 160, 0, stream>>>((int4*)bcnt, 160);
        chist_k<<<nblkA, 1024, 0, stream>>>(rows, bcnt, nnz);
        bscan_k<<<1, 1024, 0, stream>>>(bcnt, bbase, gcur, nnz);
        passA_k<<<nblkA, 1024, 0, stream>>>(rows, cols, vals, gcur, stage, nnz);
        passB_k<<<NBC, blk, 0, stream>>>(stage, bbase, offs, edges);

        init_k<<<grid_n4, blk, 0, stream>>>((const float4*)user_emb,
                                            (const float4*)item_emb,
                                            (float4*)acc, (uint2*)hb0);

        const int grid_sp = (int)(((size_t)NN * 64) / blk);   // 37500
        spmm_g<1><<<grid_sp, blk, 0, stream>>>(offs, edges, (const unsigned int*)hb0,
                                               hb1, (float4*)acc);
        spmm_g<1><<<grid_sp, blk, 0, stream>>>(offs, edges, (const unsigned int*)hb1,
                                               hb0, (float4*)acc);
        spmm_g<2><<<grid_sp, blk, 0, stream>>>(offs, edges, (const unsigned int*)hb0,
                                               nullptr, (float4*)acc);

        epi_k<<<(u4 + blk - 1) / blk, blk, 0, stream>>>((const float4*)acc,
            (const float4*)mask, (float4*)masked_out, (float4*)mask_out);
        attr_gemm_k<<<NU / 4, blk, 0, stream>>>(masked_out, W, b, pred_out);
    } else {
        // fallback: atomic scatter path entirely in d_out
        float* h0 = out + N64;
        float* h1 = out + 2 * N64;
        finit_k<<<grid_n4, blk, 0, stream>>>((const float4*)user_emb,
                                             (const float4*)item_emb,
                                             (float4*)acc, (float4*)h0, (float4*)h1);
        const long long st = (long long)nnz * 64;
        const int grid_sc = (int)((st + blk - 1) / blk);
        spmm_atomic_k<<<grid_sc, blk, 0, stream>>>(rows, cols, vals, h0, h1, nnz);
        addzero_k<<<grid_n4, blk, 0, stream>>>((float4*)acc, (const float4*)h1, (float4*)h0);
        spmm_atomic_k<<<grid_sc, blk, 0, stream>>>(rows, cols, vals, h1, h0, nnz);
        addzero_k<<<grid_n4, blk, 0, stream>>>((float4*)acc, (const float4*)h0, (float4*)h1);
        spmm_atomic_k<<<grid_sc, blk, 0, stream>>>(rows, cols, vals, h0, h1, nnz);
        final_k<<<grid_n4, blk, 0, stream>>>((float4*)acc, (const float4*)h1,
                                             (const float4*)mask, (float4*)masked_out);
        attr_gemm_k<<<NU / 4, blk, 0, stream>>>(masked_out, W, b, pred_out);
        copy_k<<<(u4 + blk - 1) / blk, blk, 0, stream>>>((const float4*)mask,
                                                         (float4*)mask_out, u4);
    }
}

// Round 7
// 522.747 us; speedup vs baseline: 6.2972x; 1.1719x over previous
//
#include <hip/hip_runtime.h>

constexpr int NU = 100000;
constexpr int NI = 50000;
constexpr int NN = 150000;
constexpr int EMB = 64;
constexpr size_t U64 = (size_t)NU * EMB;   // 6,400,000
constexpr size_t N64 = (size_t)NN * EMB;   // 9,600,000
constexpr int BKR = 1024;                  // rows per coarse bucket
constexpr int NBC = (NN + BKR - 1) / BKR;  // 147 buckets
constexpr int CHUNK_A = 4864;              // edges per passA block (LDS-bound)
constexpr int CHUNK_H = 32768;             // edges per chist block

// ---------- bf16 pack (RNE) ----------
__device__ inline unsigned int bfp(float a, float b) {
    unsigned int ua = __float_as_uint(a), ub = __float_as_uint(b);
    ua += 0x7fffu + ((ua >> 16) & 1u);
    ub += 0x7fffu + ((ub >> 16) & 1u);
    return (ua >> 16) | (ub & 0xffff0000u);
}

// ======================= CSR build =======================

__global__ void zero_k(int* __restrict__ p, int n) {
    int i = blockIdx.x * blockDim.x + threadIdx.x;
    if (i < n) p[i] = 0;
}

// coarse bucket histogram via LDS (no per-edge global atomics)
__global__ __launch_bounds__(1024) void chist_k(const int* __restrict__ rows,
                                                int* __restrict__ bcnt, int nnz) {
    __shared__ int lh[NBC];
    int t = threadIdx.x;
    if (t < NBC) lh[t] = 0;
    __syncthreads();
    int cb = blockIdx.x * CHUNK_H;
    int ce = min(cb + CHUNK_H, nnz);
    for (int i = cb + t; i < ce; i += 1024) atomicAdd(&lh[rows[i] >> 10], 1);
    __syncthreads();
    if (t < NBC) {
        int v = lh[t];
        if (v) atomicAdd(&bcnt[t], v);
    }
}

// scan of 147 bucket counts -> bbase[0..NBC] (bbase[NBC]=nnz), init gcur
__global__ __launch_bounds__(256) void bscan_k(const int* __restrict__ bcnt,
                                               int* __restrict__ bbase,
                                               int* __restrict__ gcur, int nnz) {
    __shared__ int part[256];
    int t = threadIdx.x;
    int v = (t < NBC) ? bcnt[t] : 0;
    part[t] = v;
    __syncthreads();
    for (int d = 1; d < 256; d <<= 1) {
        int u = (t >= d) ? part[t - d] : 0;
        __syncthreads();
        part[t] += u;
        __syncthreads();
    }
    if (t < NBC) {
        int e = part[t] - v;
        bbase[t] = e;
        gcur[t] = e;
    }
    if (t == 0) bbase[NBC] = nnz;
}

// pass A: sequential-read chunk sort. Phase 3 scatters packed edges into LDS
// at their rank (plus per-edge bucket shift); phase 4 emits LDS sequentially
// -> global reads AND writes are coalesced; no random global access at all.
__global__ __launch_bounds__(1024) void passA_k(const int* __restrict__ rows,
                                                const int* __restrict__ cols,
                                                const float* __restrict__ vals,
                                                int* __restrict__ gcur,
                                                int2* __restrict__ stage, int nnz) {
    __shared__ int lhist[NBC];
    __shared__ int shiftb[NBC];
    __shared__ int lcur[NBC];
    __shared__ int part[1024];
    __shared__ int2 ebuf[CHUNK_A];
    __shared__ int eshift[CHUNK_A];
    int t = threadIdx.x;
    int cb = blockIdx.x * CHUNK_A;
    int ce = min(cb + CHUNK_A, nnz);
    if (t < NBC) lhist[t] = 0;
    __syncthreads();
    for (int i = cb + t; i < ce; i += 1024) atomicAdd(&lhist[rows[i] >> 10], 1);
    __syncthreads();
    part[t] = (t < NBC) ? lhist[t] : 0;
    __syncthreads();
    for (int d = 1; d < 1024; d <<= 1) {
        int v = (t >= d) ? part[t - d] : 0;
        __syncthreads();
        part[t] += v;
        __syncthreads();
    }
    if (t < NBC) {
        int cnt = lhist[t];
        int lo = part[t] - cnt;           // local exclusive offset
        lcur[t] = lo;
        int gb = cnt ? atomicAdd(&gcur[t], cnt) : 0;
        shiftb[t] = gb - lo;
    }
    __syncthreads();
    for (int i = cb + t; i < ce; i += 1024) {
        int r = rows[i];
        int bk = r >> 10;
        int d = atomicAdd(&lcur[bk], 1);
        ebuf[d] = make_int2(cols[i] | ((r & 1023) << 18), __float_as_int(vals[i]));
        eshift[d] = shiftb[bk];
    }
    __syncthreads();
    int n = ce - cb;
    for (int dst = t; dst < n; dst += 1024) {
        stage[eshift[dst] + dst] = ebuf[dst];
    }
}

// pass B: per coarse bucket (1024 rows, ~261KB L2-hot window) — build exact
// per-row offsets in LDS (writes offs) and scatter edges to CSR positions.
__global__ __launch_bounds__(1024) void passB_k(const int2* __restrict__ stage,
                                                const int* __restrict__ bbase,
                                                int* __restrict__ offs,
                                                int2* __restrict__ edges) {
    __shared__ int part[1024];
    __shared__ int lcur[1024];
    int b = blockIdx.x;
    int t = threadIdx.x;
    int beg = bbase[b];
    int end = bbase[b + 1];
    lcur[t] = 0;
    __syncthreads();
    for (int i = beg + t; i < end; i += 1024) {
        atomicAdd(&lcur[(stage[i].x >> 18) & 1023], 1);
    }
    __syncthreads();
    int v = lcur[t];
    part[t] = v;
    __syncthreads();
    for (int d = 1; d < 1024; d <<= 1) {
        int u = (t >= d) ? part[t - d] : 0;
        __syncthreads();
        part[t] += u;
        __syncthreads();
    }
    int rowoff = beg + part[t] - v;       // global CSR offset for row b*1024+t
    lcur[t] = rowoff;
    offs[b * 1024 + t] = rowoff;          // rows >= NN get end-of-bucket; offs[NN]=nnz
    __syncthreads();
    for (int i = beg + t; i < end; i += 1024) {
        int2 e = stage[i];
        int lrow = (e.x >> 18) & 1023;
        int pos = atomicAdd(&lcur[lrow], 1);
        edges[pos] = make_int2(e.x & 0x3ffff, e.y);
    }
}

// ======================= init: acc = emb (f32), hb0 = bf16(emb) =======================
__global__ void init_k(const float4* __restrict__ ue, const float4* __restrict__ ie,
                       float4* __restrict__ acc, uint2* __restrict__ hb0) {
    int i = blockIdx.x * blockDim.x + threadIdx.x;
    const int n4 = (int)(N64 / 4);
    if (i >= n4) return;
    const int u4 = (int)(U64 / 4);
    float4 v = (i < u4) ? ue[i] : ie[i - u4];
    acc[i] = v;
    hb0[i] = make_uint2(bfp(v.x, v.y), bfp(v.z, v.w));
}

// ======================= CSR row-gather SpMM (bf16 x) =======================
template<int MODE>
__global__ __launch_bounds__(256) void spmm_g(
    const int* __restrict__ offs, const int2* __restrict__ edges,
    const unsigned int* __restrict__ xb,
    uint2* __restrict__ yb, float4* __restrict__ acc) {
    int w = (blockIdx.x * 256 + (int)threadIdx.x) >> 6;
    int lane = threadIdx.x & 63;
    if (w >= NN) return;
    int beg = offs[w], end = offs[w + 1];
    int g = lane >> 4, gl = lane & 15;
    float4 s = make_float4(0.f, 0.f, 0.f, 0.f);
    for (int p = beg; p < end; p += 32) {
        int idx = p + lane;
        int2 e = (lane < 32 && idx < end) ? edges[idx] : make_int2(0, 0);
        #pragma unroll
        for (int j = 0; j < 8; ++j) {
            int src = g * 8 + j;
            int c = __shfl(e.x, src);
            float v = __int_as_float(__shfl(e.y, src));
            uint2 u = *(const uint2*)(xb + (size_t)c * 32 + gl * 2);
            float x0 = __uint_as_float(u.x << 16);
            float x1 = __uint_as_float(u.x & 0xffff0000u);
            float x2 = __uint_as_float(u.y << 16);
            float x3 = __uint_as_float(u.y & 0xffff0000u);
            s.x += v * x0; s.y += v * x1; s.z += v * x2; s.w += v * x3;
        }
    }
    #pragma unroll
    for (int d = 16; d <= 32; d <<= 1) {
        s.x += __shfl_xor(s.x, d);
        s.y += __shfl_xor(s.y, d);
        s.z += __shfl_xor(s.z, d);
        s.w += __shfl_xor(s.w, d);
    }
    if (lane < 16) {
        size_t o = (size_t)w * 16 + gl;
        if (MODE == 1) {
            yb[o] = make_uint2(bfp(s.x, s.y), bfp(s.z, s.w));
            float4 a = acc[o];
            acc[o] = make_float4(a.x + s.x, a.y + s.y, a.z + s.z, a.w + s.w);
        } else {
            float4 a = acc[o];
            acc[o] = make_float4((a.x + s.x) * 0.25f, (a.y + s.y) * 0.25f,
                                 (a.z + s.z) * 0.25f, (a.w + s.w) * 0.25f);
        }
    }
}

// ======================= epilogue =======================

__global__ void epi_k(const float4* __restrict__ comb, const float4* __restrict__ mask,
                      float4* __restrict__ masked, float4* __restrict__ mout) {
    int i = blockIdx.x * blockDim.x + threadIdx.x;
    const int u4 = (int)(U64 / 4);
    if (i >= u4) return;
    float4 c = comb[i], m = mask[i];
    masked[i] = make_float4(c.x * m.x, c.y * m.y, c.z * m.z, c.w * m.w);
    mout[i] = m;
}

__global__ __launch_bounds__(256) void attr_gemm_k(const float* __restrict__ masked,
                                                   const float* __restrict__ W,
                                                   const float* __restrict__ b,
                                                   float* __restrict__ out) {
    __shared__ float Wl[64 * 64];
    __shared__ float bl[64];
    int t = threadIdx.x;
    #pragma unroll
    for (int k = 0; k < 16; ++k) Wl[t + 256 * k] = W[t + 256 * k];
    if (t < 64) bl[t] = b[t];
    __syncthreads();
    int wave = t >> 6, lane = t & 63;
    int row = blockIdx.x * 4 + wave;
    if (row >= NU) return;
    float mval = masked[(size_t)row * EMB + lane];
    float sum = bl[lane];
    #pragma unroll
    for (int k = 0; k < 64; ++k) {
        sum += __shfl(mval, k) * Wl[k * 64 + lane];
    }
    out[(size_t)row * EMB + lane] = fmaxf(sum, 0.f);
}

// ======================= fallback (atomic path) =======================

__global__ void finit_k(const float4* __restrict__ ue, const float4* __restrict__ ie,
                        float4* __restrict__ acc, float4* __restrict__ h0,
                        float4* __restrict__ h1) {
    int i = blockIdx.x * blockDim.x + threadIdx.x;
    const int n4 = (int)(N64 / 4);
    if (i >= n4) return;
    const int u4 = (int)(U64 / 4);
    float4 v = (i < u4) ? ue[i] : ie[i - u4];
    acc[i] = v; h0[i] = v; h1[i] = make_float4(0.f, 0.f, 0.f, 0.f);
}

__global__ void spmm_atomic_k(const int* __restrict__ rows, const int* __restrict__ cols,
                              const float* __restrict__ vals,
                              const float* __restrict__ x, float* __restrict__ y, int nnz) {
    int e = (blockIdx.x * blockDim.x + threadIdx.x) >> 6;
    int lane = threadIdx.x & 63;
    if (e >= nnz) return;
    int r = rows[e]; int c = cols[e]; float v = vals[e];
    atomicAdd(&y[(size_t)r * EMB + lane], x[(size_t)c * EMB + lane] * v);
}

__global__ void addzero_k(float4* __restrict__ acc, const float4* __restrict__ hin,
                          float4* __restrict__ hz) {
    int i = blockIdx.x * blockDim.x + threadIdx.x;
    const int n4 = (int)(N64 / 4);
    if (i >= n4) return;
    float4 a = acc[i]; float4 b = hin[i];
    a.x += b.x; a.y += b.y; a.z += b.z; a.w += b.w;
    acc[i] = a; hz[i] = make_float4(0.f, 0.f, 0.f, 0.f);
}

__global__ void final_k(float4* __restrict__ acc_io, const float4* __restrict__ hlast,
                        const float4* __restrict__ mask, float4* __restrict__ masked_out) {
    int i = blockIdx.x * blockDim.x + threadIdx.x;
    const int n4 = (int)(N64 / 4);
    if (i >= n4) return;
    float4 a = acc_io[i]; float4 h = hlast[i];
    float4 c = make_float4((a.x + h.x) * 0.25f, (a.y + h.y) * 0.25f,
                           (a.z + h.z) * 0.25f, (a.w + h.w) * 0.25f);
    acc_io[i] = c;
    const int u4 = (int)(U64 / 4);
    if (i < u4) {
        float4 m = mask[i];
        masked_out[i] = make_float4(c.x * m.x, c.y * m.y, c.z * m.z, c.w * m.w);
    }
}

__global__ void copy_k(const float4* __restrict__ src, float4* __restrict__ dst, int n4) {
    int i = blockIdx.x * blockDim.x + threadIdx.x;
    if (i < n4) dst[i] = src[i];
}

// ======================= launch =======================

extern "C" void kernel_launch(void* const* d_in, const int* in_sizes, int n_in,
                              void* d_out, int out_size, void* d_ws, size_t ws_size,
                              hipStream_t stream) {
    const float* user_emb = (const float*)d_in[0];
    const float* item_emb = (const float*)d_in[1];
    const int*   rows     = (const int*)d_in[2];
    const int*   cols     = (const int*)d_in[3];
    const float* vals     = (const float*)d_in[4];
    const float* mask     = (const float*)d_in[5];
    const float* W        = (const float*)d_in[6];
    const float* b        = (const float*)d_in[7];
    float* out = (float*)d_out;
    const int nnz = in_sizes[2];

    float* acc = out;                         // -> user_final || item_final
    float* masked_out = out + N64;
    float* pred_out   = out + N64 + U64;
    float* mask_out   = out + N64 + 2 * U64;

    const int blk = 256;
    const int n4 = (int)(N64 / 4);
    const int grid_n4 = (n4 + blk - 1) / blk;
    const int u4 = (int)(U64 / 4);

    // ws carve: bcnt | bbase | gcur | offs | edges
    int* bcnt  = (int*)d_ws;                  // 256
    int* bbase = bcnt + 256;                  // 256 (NBC+1 used)
    int* gcur  = bbase + 256;                 // 256
    int* offs  = gcur + 256;                  // NBC*1024 = 150528
    int2* edges = (int2*)(offs + 150784);     // 8B-aligned
    const size_t need = (256 * 3 + 150784) * 4 + (size_t)nnz * 8 + 64;

    if (ws_size >= need) {
        // stage lives in d_out's h-region (dead until init_k)
        int2* stage = (int2*)(out + N64);
        uint2* hb0 = (uint2*)(out + N64);                 // 19.2 MB
        uint2* hb1 = hb0 + (N64 / 4);

        zero_k<<<1, 256, 0, stream>>>(bcnt, 256);
        chist_k<<<(nnz + CHUNK_H - 1) / CHUNK_H, 1024, 0, stream>>>(rows, bcnt, nnz);
        bscan_k<<<1, 256, 0, stream>>>(bcnt, bbase, gcur, nnz);
        passA_k<<<(nnz + CHUNK_A - 1) / CHUNK_A, 1024, 0, stream>>>(rows, cols, vals,
                                                                    gcur, stage, nnz);
        passB_k<<<NBC, 1024, 0, stream>>>(stage, bbase, offs, edges);

        init_k<<<grid_n4, blk, 0, stream>>>((const float4*)user_emb,
                                            (const float4*)item_emb,
                                            (float4*)acc, (uint2*)hb0);

        const int grid_sp = (int)(((size_t)NN * 64) / blk);   // 37500
        spmm_g<1><<<grid_sp, blk, 0, stream>>>(offs, edges, (const unsigned int*)hb0,
                                               hb1, (float4*)acc);
        spmm_g<1><<<grid_sp, blk, 0, stream>>>(offs, edges, (const unsigned int*)hb1,
                                               hb0, (float4*)acc);
        spmm_g<2><<<grid_sp, blk, 0, stream>>>(offs, edges, (const unsigned int*)hb0,
                                               nullptr, (float4*)acc);

        epi_k<<<(u4 + blk - 1) / blk, blk, 0, stream>>>((const float4*)acc,
            (const float4*)mask, (float4*)masked_out, (float4*)mask_out);
        attr_gemm_k<<<NU / 4, blk, 0, stream>>>(masked_out, W, b, pred_out);
    } else {
        // fallback: atomic scatter path entirely in d_out
        float* h0 = out + N64;
        float* h1 = out + 2 * N64;
        finit_k<<<grid_n4, blk, 0, stream>>>((const float4*)user_emb,
                                             (const float4*)item_emb,
                                             (float4*)acc, (float4*)h0, (float4*)h1);
        const long long st = (long long)nnz * 64;
        const int grid_sc = (int)((st + blk - 1) / blk);
        spmm_atomic_k<<<grid_sc, blk, 0, stream>>>(rows, cols, vals, h0, h1, nnz);
        addzero_k<<<grid_n4, blk, 0, stream>>>((float4*)acc, (const float4*)h1, (float4*)h0);
        spmm_atomic_k<<<grid_sc, blk, 0, stream>>>(rows, cols, vals, h1, h0, nnz);
        addzero_k<<<grid_n4, blk, 0, stream>>>((float4*)acc, (const float4*)h0, (float4*)h1);
        spmm_atomic_k<<<grid_sc, blk, 0, stream>>>(rows, cols, vals, h0, h1, nnz);
        final_k<<<grid_n4, blk, 0, stream>>>((float4*)acc, (const float4*)h1,
                                             (const float4*)mask, (float4*)masked_out);
        attr_gemm_k<<<NU / 4, blk, 0, stream>>>(masked_out, W, b, pred_out);
        copy_k<<<(u4 + blk - 1) / blk, blk, 0, stream>>>((const float4*)mask,
                                                         (float4*)mask_out, u4);
    }
}

// Round 8
// 441.160 us; speedup vs baseline: 7.4618x; 1.1849x over previous
//
#include <hip/hip_runtime.h>

constexpr int NU = 100000;
constexpr int NI = 50000;
constexpr int NN = 150000;
constexpr int EMB = 64;
constexpr size_t U64 = (size_t)NU * EMB;   // 6,400,000
constexpr size_t N64 = (size_t)NN * EMB;   // 9,600,000
constexpr int BKR = 1024;                  // rows per coarse bucket
constexpr int NBC = (NN + BKR - 1) / BKR;  // 147 buckets
constexpr int CHUNK_A = 4864;              // edges per passA block (LDS-bound)
constexpr int CHUNK_H = 32768;             // edges per chist block

// ---------- bf16 pack (RNE) ----------
__device__ inline unsigned int bfp(float a, float b) {
    unsigned int ua = __float_as_uint(a), ub = __float_as_uint(b);
    ua += 0x7fffu + ((ua >> 16) & 1u);
    ub += 0x7fffu + ((ub >> 16) & 1u);
    return (ua >> 16) | (ub & 0xffff0000u);
}

// ======================= CSR build =======================

__global__ void zero_k(int* __restrict__ p, int n) {
    int i = blockIdx.x * blockDim.x + threadIdx.x;
    if (i < n) p[i] = 0;
}

// coarse bucket histogram via LDS (no per-edge global atomics)
__global__ __launch_bounds__(1024) void chist_k(const int* __restrict__ rows,
                                                int* __restrict__ bcnt, int nnz) {
    __shared__ int lh[NBC];
    int t = threadIdx.x;
    if (t < NBC) lh[t] = 0;
    __syncthreads();
    int cb = blockIdx.x * CHUNK_H;
    int ce = min(cb + CHUNK_H, nnz);
    for (int i = cb + t; i < ce; i += 1024) atomicAdd(&lh[rows[i] >> 10], 1);
    __syncthreads();
    if (t < NBC) {
        int v = lh[t];
        if (v) atomicAdd(&bcnt[t], v);
    }
}

// scan of 147 bucket counts -> bbase[0..NBC] (bbase[NBC]=nnz), init gcur
__global__ __launch_bounds__(256) void bscan_k(const int* __restrict__ bcnt,
                                               int* __restrict__ bbase,
                                               int* __restrict__ gcur, int nnz) {
    __shared__ int part[256];
    int t = threadIdx.x;
    int v = (t < NBC) ? bcnt[t] : 0;
    part[t] = v;
    __syncthreads();
    for (int d = 1; d < 256; d <<= 1) {
        int u = (t >= d) ? part[t - d] : 0;
        __syncthreads();
        part[t] += u;
        __syncthreads();
    }
    if (t < NBC) {
        int e = part[t] - v;
        bbase[t] = e;
        gcur[t] = e;
    }
    if (t == 0) bbase[NBC] = nnz;
}

// pass A: sequential-read chunk sort; permutation done entirely in LDS;
// global reads AND writes coalesced.
__global__ __launch_bounds__(1024) void passA_k(const int* __restrict__ rows,
                                                const int* __restrict__ cols,
                                                const float* __restrict__ vals,
                                                int* __restrict__ gcur,
                                                int2* __restrict__ stage, int nnz) {
    __shared__ int lhist[NBC];
    __shared__ int shiftb[NBC];
    __shared__ int lcur[NBC];
    __shared__ int part[1024];
    __shared__ int2 ebuf[CHUNK_A];
    __shared__ int eshift[CHUNK_A];
    int t = threadIdx.x;
    int cb = blockIdx.x * CHUNK_A;
    int ce = min(cb + CHUNK_A, nnz);
    if (t < NBC) lhist[t] = 0;
    __syncthreads();
    for (int i = cb + t; i < ce; i += 1024) atomicAdd(&lhist[rows[i] >> 10], 1);
    __syncthreads();
    part[t] = (t < NBC) ? lhist[t] : 0;
    __syncthreads();
    for (int d = 1; d < 1024; d <<= 1) {
        int v = (t >= d) ? part[t - d] : 0;
        __syncthreads();
        part[t] += v;
        __syncthreads();
    }
    if (t < NBC) {
        int cnt = lhist[t];
        int lo = part[t] - cnt;           // local exclusive offset
        lcur[t] = lo;
        int gb = cnt ? atomicAdd(&gcur[t], cnt) : 0;
        shiftb[t] = gb - lo;
    }
    __syncthreads();
    for (int i = cb + t; i < ce; i += 1024) {
        int r = rows[i];
        int bk = r >> 10;
        int d = atomicAdd(&lcur[bk], 1);
        ebuf[d] = make_int2(cols[i] | ((r & 1023) << 18), __float_as_int(vals[i]));
        eshift[d] = shiftb[bk];
    }
    __syncthreads();
    int n = ce - cb;
    for (int dst = t; dst < n; dst += 1024) {
        stage[eshift[dst] + dst] = ebuf[dst];
    }
}

// pass B: per coarse bucket (1024 rows, L2-hot window) — per-row offs + scatter
__global__ __launch_bounds__(1024) void passB_k(const int2* __restrict__ stage,
                                                const int* __restrict__ bbase,
                                                int* __restrict__ offs,
                                                int2* __restrict__ edges) {
    __shared__ int part[1024];
    __shared__ int lcur[1024];
    int b = blockIdx.x;
    int t = threadIdx.x;
    int beg = bbase[b];
    int end = bbase[b + 1];
    lcur[t] = 0;
    __syncthreads();
    for (int i = beg + t; i < end; i += 1024) {
        atomicAdd(&lcur[(stage[i].x >> 18) & 1023], 1);
    }
    __syncthreads();
    int v = lcur[t];
    part[t] = v;
    __syncthreads();
    for (int d = 1; d < 1024; d <<= 1) {
        int u = (t >= d) ? part[t - d] : 0;
        __syncthreads();
        part[t] += u;
        __syncthreads();
    }
    int rowoff = beg + part[t] - v;       // global CSR offset for row b*1024+t
    lcur[t] = rowoff;
    offs[b * 1024 + t] = rowoff;          // rows >= NN get end-of-bucket; offs[NN]=nnz
    __syncthreads();
    for (int i = beg + t; i < end; i += 1024) {
        int2 e = stage[i];
        int lrow = (e.x >> 18) & 1023;
        int pos = atomicAdd(&lcur[lrow], 1);
        edges[pos] = make_int2(e.x & 0x3ffff, e.y);
    }
}

// ======================= init: acc = emb (f32), hb0 = bf16(emb) =======================
__global__ void init_k(const float4* __restrict__ ue, const float4* __restrict__ ie,
                       float4* __restrict__ acc, uint2* __restrict__ hb0) {
    int i = blockIdx.x * blockDim.x + threadIdx.x;
    const int n4 = (int)(N64 / 4);
    if (i >= n4) return;
    const int u4 = (int)(U64 / 4);
    float4 v = (i < u4) ? ue[i] : ie[i - u4];
    acc[i] = v;
    hb0[i] = make_uint2(bfp(v.x, v.y), bfp(v.z, v.w));
}

// ======================= CSR row-gather SpMM (bf16 x) =======================
template<int MODE>
__global__ __launch_bounds__(256) void spmm_g(
    const int* __restrict__ offs, const int2* __restrict__ edges,
    const unsigned int* __restrict__ xb,
    uint2* __restrict__ yb, float4* __restrict__ acc) {
    int w = (blockIdx.x * 256 + (int)threadIdx.x) >> 6;
    int lane = threadIdx.x & 63;
    if (w >= NN) return;
    int beg = offs[w], end = offs[w + 1];
    int g = lane >> 4, gl = lane & 15;
    float4 s = make_float4(0.f, 0.f, 0.f, 0.f);
    for (int p = beg; p < end; p += 32) {
        int idx = p + lane;
        int2 e = (lane < 32 && idx < end) ? edges[idx] : make_int2(0, 0);
        #pragma unroll
        for (int j = 0; j < 8; ++j) {
            int src = g * 8 + j;
            int c = __shfl(e.x, src);
            float v = __int_as_float(__shfl(e.y, src));
            uint2 u = *(const uint2*)(xb + (size_t)c * 32 + gl * 2);
            float x0 = __uint_as_float(u.x << 16);
            float x1 = __uint_as_float(u.x & 0xffff0000u);
            float x2 = __uint_as_float(u.y << 16);
            float x3 = __uint_as_float(u.y & 0xffff0000u);
            s.x += v * x0; s.y += v * x1; s.z += v * x2; s.w += v * x3;
        }
    }
    #pragma unroll
    for (int d = 16; d <= 32; d <<= 1) {
        s.x += __shfl_xor(s.x, d);
        s.y += __shfl_xor(s.y, d);
        s.z += __shfl_xor(s.z, d);
        s.w += __shfl_xor(s.w, d);
    }
    if (lane < 16) {
        size_t o = (size_t)w * 16 + gl;
        if (MODE == 1) {
            yb[o] = make_uint2(bfp(s.x, s.y), bfp(s.z, s.w));
            float4 a = acc[o];
            acc[o] = make_float4(a.x + s.x, a.y + s.y, a.z + s.z, a.w + s.w);
        } else {
            float4 a = acc[o];
            acc[o] = make_float4((a.x + s.x) * 0.25f, (a.y + s.y) * 0.25f,
                                 (a.z + s.z) * 0.25f, (a.w + s.w) * 0.25f);
        }
    }
}

// ======================= epilogue =======================

__global__ void epi_k(const float4* __restrict__ comb, const float4* __restrict__ mask,
                      float4* __restrict__ masked, float4* __restrict__ mout) {
    int i = blockIdx.x * blockDim.x + threadIdx.x;
    const int u4 = (int)(U64 / 4);
    if (i >= u4) return;
    float4 c = comb[i], m = mask[i];
    masked[i] = make_float4(c.x * m.x, c.y * m.y, c.z * m.z, c.w * m.w);
    mout[i] = m;
}

// tiled f32 GEMM: 64-row tile/block, 4x4 register sub-tile/thread
__global__ __launch_bounds__(256) void attr_gemm_k(const float* __restrict__ masked,
                                                   const float* __restrict__ W,
                                                   const float* __restrict__ bias,
                                                   float* __restrict__ out) {
    __shared__ float mt[64][68];   // m tile, row-major, stride 68 (16B-aligned rows)
    __shared__ float Wt[64][68];   // W, row-major, stride 68
    __shared__ float bl[64];
    int t = threadIdx.x;
    int rowbase = blockIdx.x * 64;
    const float4* W4 = (const float4*)W;
    #pragma unroll
    for (int j = 0; j < 4; ++j) {
        int idx = t + 256 * j;                 // float4 index in 64x64
        float4 w = W4[idx];
        *(float4*)&Wt[idx >> 4][(idx & 15) * 4] = w;
    }
    if (t < 64) bl[t] = bias[t];
    const float4* M4 = (const float4*)(masked + (size_t)rowbase * 64);
    #pragma unroll
    for (int j = 0; j < 4; ++j) {
        int idx = t + 256 * j;
        float4 m = M4[idx];                    // tail rows read scratch (guarded on store)
        *(float4*)&mt[idx >> 4][(idx & 15) * 4] = m;
    }
    __syncthreads();
    int r0 = (t >> 4) * 4, c0 = (t & 15) * 4;
    float a0x = 0, a0y = 0, a0z = 0, a0w = 0;
    float a1x = 0, a1y = 0, a1z = 0, a1w = 0;
    float a2x = 0, a2y = 0, a2z = 0, a2w = 0;
    float a3x = 0, a3y = 0, a3z = 0, a3w = 0;
    #pragma unroll 8
    for (int k = 0; k < 64; ++k) {
        float4 wv = *(const float4*)&Wt[k][c0];
        float m0 = mt[r0 + 0][k];
        float m1 = mt[r0 + 1][k];
        float m2 = mt[r0 + 2][k];
        float m3 = mt[r0 + 3][k];
        a0x += m0 * wv.x; a0y += m0 * wv.y; a0z += m0 * wv.z; a0w += m0 * wv.w;
        a1x += m1 * wv.x; a1y += m1 * wv.y; a1z += m1 * wv.z; a1w += m1 * wv.w;
        a2x += m2 * wv.x; a2y += m2 * wv.y; a2z += m2 * wv.z; a2w += m2 * wv.w;
        a3x += m3 * wv.x; a3y += m3 * wv.y; a3z += m3 * wv.z; a3w += m3 * wv.w;
    }
    float4 bv = *(const float4*)&bl[c0];
    float rx[4][4] = {{a0x, a0y, a0z, a0w}, {a1x, a1y, a1z, a1w},
                      {a2x, a2y, a2z, a2w}, {a3x, a3y, a3z, a3w}};
    #pragma unroll
    for (int i = 0; i < 4; ++i) {
        int r = rowbase + r0 + i;
        if (r < NU) {
            float4 o;
            o.x = fmaxf(rx[i][0] + bv.x, 0.f);
            o.y = fmaxf(rx[i][1] + bv.y, 0.f);
            o.z = fmaxf(rx[i][2] + bv.z, 0.f);
            o.w = fmaxf(rx[i][3] + bv.w, 0.f);
            *(float4*)&out[(size_t)r * 64 + c0] = o;
        }
    }
}

// ======================= fallback (atomic path) =======================

__global__ void finit_k(const float4* __restrict__ ue, const float4* __restrict__ ie,
                        float4* __restrict__ acc, float4* __restrict__ h0,
                        float4* __restrict__ h1) {
    int i = blockIdx.x * blockDim.x + threadIdx.x;
    const int n4 = (int)(N64 / 4);
    if (i >= n4) return;
    const int u4 = (int)(U64 / 4);
    float4 v = (i < u4) ? ue[i] : ie[i - u4];
    acc[i] = v; h0[i] = v; h1[i] = make_float4(0.f, 0.f, 0.f, 0.f);
}

__global__ void spmm_atomic_k(const int* __restrict__ rows, const int* __restrict__ cols,
                              const float* __restrict__ vals,
                              const float* __restrict__ x, float* __restrict__ y, int nnz) {
    int e = (blockIdx.x * blockDim.x + threadIdx.x) >> 6;
    int lane = threadIdx.x & 63;
    if (e >= nnz) return;
    int r = rows[e]; int c = cols[e]; float v = vals[e];
    atomicAdd(&y[(size_t)r * EMB + lane], x[(size_t)c * EMB + lane] * v);
}

__global__ void addzero_k(float4* __restrict__ acc, const float4* __restrict__ hin,
                          float4* __restrict__ hz) {
    int i = blockIdx.x * blockDim.x + threadIdx.x;
    const int n4 = (int)(N64 / 4);
    if (i >= n4) return;
    float4 a = acc[i]; float4 b = hin[i];
    a.x += b.x; a.y += b.y; a.z += b.z; a.w += b.w;
    acc[i] = a; hz[i] = make_float4(0.f, 0.f, 0.f, 0.f);
}

__global__ void final_k(float4* __restrict__ acc_io, const float4* __restrict__ hlast,
                        const float4* __restrict__ mask, float4* __restrict__ masked_out) {
    int i = blockIdx.x * blockDim.x + threadIdx.x;
    const int n4 = (int)(N64 / 4);
    if (i >= n4) return;
    float4 a = acc_io[i]; float4 h = hlast[i];
    float4 c = make_float4((a.x + h.x) * 0.25f, (a.y + h.y) * 0.25f,
                           (a.z + h.z) * 0.25f, (a.w + h.w) * 0.25f);
    acc_io[i] = c;
    const int u4 = (int)(U64 / 4);
    if (i < u4) {
        float4 m = mask[i];
        masked_out[i] = make_float4(c.x * m.x, c.y * m.y, c.z * m.z, c.w * m.w);
    }
}

__global__ void copy_k(const float4* __restrict__ src, float4* __restrict__ dst, int n4) {
    int i = blockIdx.x * blockDim.x + threadIdx.x;
    if (i < n4) dst[i] = src[i];
}

// ======================= launch =======================

extern "C" void kernel_launch(void* const* d_in, const int* in_sizes, int n_in,
                              void* d_out, int out_size, void* d_ws, size_t ws_size,
                              hipStream_t stream) {
    const float* user_emb = (const float*)d_in[0];
    const float* item_emb = (const float*)d_in[1];
    const int*   rows     = (const int*)d_in[2];
    const int*   cols     = (const int*)d_in[3];
    const float* vals     = (const float*)d_in[4];
    const float* mask     = (const float*)d_in[5];
    const float* W        = (const float*)d_in[6];
    const float* b        = (const float*)d_in[7];
    float* out = (float*)d_out;
    const int nnz = in_sizes[2];

    float* acc = out;                         // -> user_final || item_final
    float* masked_out = out + N64;
    float* pred_out   = out + N64 + U64;
    float* mask_out   = out + N64 + 2 * U64;

    const int blk = 256;
    const int n4 = (int)(N64 / 4);
    const int grid_n4 = (n4 + blk - 1) / blk;
    const int u4 = (int)(U64 / 4);
    const int grid_attr = (NU + 63) / 64;     // 1563

    // ws carve: bcnt | bbase | gcur | offs | edges
    int* bcnt  = (int*)d_ws;                  // 256
    int* bbase = bcnt + 256;                  // 256 (NBC+1 used)
    int* gcur  = bbase + 256;                 // 256
    int* offs  = gcur + 256;                  // NBC*1024 = 150528
    int2* edges = (int2*)(offs + 150784);     // 8B-aligned
    const size_t need = (256 * 3 + 150784) * 4 + (size_t)nnz * 8 + 64;

    if (ws_size >= need) {
        // stage lives in d_out's h-region (dead until init_k)
        int2* stage = (int2*)(out + N64);
        uint2* hb0 = (uint2*)(out + N64);                 // 19.2 MB
        uint2* hb1 = hb0 + (N64 / 4);

        zero_k<<<1, 256, 0, stream>>>(bcnt, 256);
        chist_k<<<(nnz + CHUNK_H - 1) / CHUNK_H, 1024, 0, stream>>>(rows, bcnt, nnz);
        bscan_k<<<1, 256, 0, stream>>>(bcnt, bbase, gcur, nnz);
        passA_k<<<(nnz + CHUNK_A - 1) / CHUNK_A, 1024, 0, stream>>>(rows, cols, vals,
                                                                    gcur, stage, nnz);
        passB_k<<<NBC, 1024, 0, stream>>>(stage, bbase, offs, edges);

        init_k<<<grid_n4, blk, 0, stream>>>((const float4*)user_emb,
                                            (const float4*)item_emb,
                                            (float4*)acc, (uint2*)hb0);

        const int grid_sp = (int)(((size_t)NN * 64) / blk);   // 37500
        spmm_g<1><<<grid_sp, blk, 0, stream>>>(offs, edges, (const unsigned int*)hb0,
                                               hb1, (float4*)acc);
        spmm_g<1><<<grid_sp, blk, 0, stream>>>(offs, edges, (const unsigned int*)hb1,
                                               hb0, (float4*)acc);
        spmm_g<2><<<grid_sp, blk, 0, stream>>>(offs, edges, (const unsigned int*)hb0,
                                               nullptr, (float4*)acc);

        epi_k<<<(u4 + blk - 1) / blk, blk, 0, stream>>>((const float4*)acc,
            (const float4*)mask, (float4*)masked_out, (float4*)mask_out);
        attr_gemm_k<<<grid_attr, blk, 0, stream>>>(masked_out, W, b, pred_out);
    } else {
        // fallback: atomic scatter path entirely in d_out
        float* h0 = out + N64;
        float* h1 = out + 2 * N64;
        finit_k<<<grid_n4, blk, 0, stream>>>((const float4*)user_emb,
                                             (const float4*)item_emb,
                                             (float4*)acc, (float4*)h0, (float4*)h1);
        const long long st = (long long)nnz * 64;
        const int grid_sc = (int)((st + blk - 1) / blk);
        spmm_atomic_k<<<grid_sc, blk, 0, stream>>>(rows, cols, vals, h0, h1, nnz);
        addzero_k<<<grid_n4, blk, 0, stream>>>((float4*)acc, (const float4*)h1, (float4*)h0);
        spmm_atomic_k<<<grid_sc, blk, 0, stream>>>(rows, cols, vals, h1, h0, nnz);
        addzero_k<<<grid_n4, blk, 0, stream>>>((float4*)acc, (const float4*)h0, (float4*)h1);
        spmm_atomic_k<<<grid_sc, blk, 0, stream>>>(rows, cols, vals, h0, h1, nnz);
        final_k<<<grid_n4, blk, 0, stream>>>((float4*)acc, (const float4*)h1,
                                             (const float4*)mask, (float4*)masked_out);
        attr_gemm_k<<<grid_attr, blk, 0, stream>>>(masked_out, W, b, pred_out);
        copy_k<<<(u4 + blk - 1) / blk, blk, 0, stream>>>((const float4*)mask,
                                                         (float4*)mask_out, u4);
    }
}